// Round 5
// baseline (21586.194 us; speedup 1.0000x reference)
//
#include <hip/hip_runtime.h>

#define BB     256
#define TSEED  120
#define PREDN  24
#define JN     15
#define HN     1024
#define DN     135
#define FN     61
#define TT     144
#define DH     256
#define BCH    32
#define RCH    (BCH*FN)   // 1952 rows per encoder chunk
#define KPF    160        // 135 padded for freq weights
#define XWP    160        // padded x width for GRU layer0
#define KP0    (XWP+HN)   // 1184
#define KP1    (2*HN)     // 2048

typedef __attribute__((ext_vector_type(8))) short short8v;
typedef __attribute__((ext_vector_type(4))) float f32x4;

__device__ __forceinline__ short f2b(float f) {
    union { float f; unsigned u; } v; v.f = f;
    unsigned r = (v.u + 0x7FFFu + ((v.u >> 16) & 1u)) >> 16;
    return (short)r;
}
__device__ __forceinline__ float b2f(short h) {
    union { unsigned u; float f; } x; x.u = ((unsigned)(unsigned short)h) << 16; return x.f;
}
__device__ __forceinline__ void fsplit(float v, short& h, short& l) {
    h = f2b(v); l = f2b(v - b2f(h));
}

// ---------------------------------------------------------------------------
// prepack: GRU fused weight, gate-INTERLEAVED packed rows:
//   n' = jb*64 + g*16 + jj   (jb = j/16, jj = j%16), g: 0=r 1=z 2=in 3=hn
//   row content: g<3 x-part = wih[g*HN+j][0:KX) ; pad to XW; recurrent part:
//   g0 += whh[j], g1 += whh[HN+j], g3 = whh[2HN+j], g2 recurrent = 0.
// ---------------------------------------------------------------------------
__global__ __launch_bounds__(256) void pack_gruw_i(const float* __restrict__ wih,
                                                   const float* __restrict__ whh,
                                                   int KX, int XW, int KP,
                                                   short* __restrict__ Wh,
                                                   short* __restrict__ Wl) {
    int np = blockIdx.x;
    int jb = np >> 6, g = (np >> 4) & 3, jj = np & 15;
    int j = jb * 16 + jj;
    for (int k = threadIdx.x; k < KP; k += 256) {
        float v = 0.f;
        if (k < KX) {
            if (g < 3) v = wih[(size_t)(g * HN + j) * KX + k];
        } else if (k >= XW) {
            int kk = k - XW;
            if (g == 0)      v = whh[(size_t)j * HN + kk];
            else if (g == 1) v = whh[(size_t)(HN + j) * HN + kk];
            else if (g == 3) v = whh[(size_t)(2 * HN + j) * HN + kk];
        }
        short hh, ll; fsplit(v, hh, ll);
        Wh[(size_t)np * KP + k] = hh;
        Wl[(size_t)np * KP + k] = ll;
    }
}

// bias pack: bp[g*HN+j]; g0=bih_r+bhh_r, g1=bih_z+bhh_z, g2=bih_n, g3=bhh_n
__global__ __launch_bounds__(256) void pack_grub(const float* __restrict__ bih,
                                                 const float* __restrict__ bhh,
                                                 float* __restrict__ bp) {
    int n = blockIdx.x * 256 + threadIdx.x;
    if (n < 4 * HN) {
        int g = n >> 10, j = n & 1023;
        float v;
        if (g == 0)      v = bih[j] + bhh[j];
        else if (g == 1) v = bih[HN + j] + bhh[HN + j];
        else if (g == 2) v = bih[2 * HN + j];
        else             v = bhh[2 * HN + j];
        bp[n] = v;
    }
}

// cast fp32 [N][K] -> bf16 pair [N][KP] zero-padded
__global__ __launch_bounds__(256) void castw(const float* __restrict__ w,
                                             short* __restrict__ oh,
                                             short* __restrict__ ol, int K, int KP) {
    int n = blockIdx.x;
    for (int k = threadIdx.x; k < KP; k += 256) {
        float v = (k < K) ? w[(size_t)n * K + k] : 0.f;
        short hh, ll; fsplit(v, hh, ll);
        oh[(size_t)n * KP + k] = hh;
        ol[(size_t)n * KP + k] = ll;
    }
}

// pack poses[:, t, :] -> X pair [t][256][XWP] (pad 135->160 zero)
__global__ __launch_bounds__(256) void pack_x(const float* __restrict__ poses,
                                              short* __restrict__ Xh,
                                              short* __restrict__ Xl) {
    int t = blockIdx.x;
    short* oh = Xh + (size_t)t * BB * XWP;
    short* ol = Xl + (size_t)t * BB * XWP;
    for (int i = threadIdx.x; i < BB * XWP; i += 256) {
        int b = i / XWP, k = i - b * XWP;
        float v = (k < DN) ? poses[((size_t)b * TT + t) * DN + k] : 0.f;
        short hh, ll; fsplit(v, hh, ll);
        oh[i] = hh; ol[i] = ll;
    }
}

// ---------------------------------------------------------------------------
// cos table + DFT (real part of rfft)
// ---------------------------------------------------------------------------
__global__ __launch_bounds__(128) void cos_kernel(float* __restrict__ cosm) {
    int f = blockIdx.x, t = threadIdx.x;
    if (t < TSEED) {
        int ft = (f * t) % TSEED;
        cosm[f * TSEED + t] = cosf((float)ft * (6.283185307179586f / (float)TSEED));
    }
}

__global__ __launch_bounds__(256) void dft_kernel(const float* __restrict__ poses,
                                                  const float* __restrict__ cosm,
                                                  float* __restrict__ freq) {
    __shared__ float cs[FN * TSEED];
    for (int i = threadIdx.x; i < FN * TSEED; i += 256) cs[i] = cosm[i];
    __syncthreads();
    const float* xp = poses + (size_t)blockIdx.x * TT * DN;
    float* fp = freq + (size_t)blockIdx.x * FN * DN;
    for (int o = threadIdx.x; o < FN * DN; o += 256) {
        int f = o / DN, d = o - f * DN;
        const float* cf = &cs[f * TSEED];
        float s = 0.f;
        #pragma unroll 4
        for (int t = 0; t < TSEED; ++t) s += xp[t * DN + d] * cf[t];
        fp[o] = s;
    }
}

// ---------------------------------------------------------------------------
// GRU scan step: one kernel per layer per time step.
// A = [A1 pair (x or h0_cur, width w1) | A2 pair (h_prev recurrent)].
// W gate-interleaved pack (see pack_gruw_i).  Grid 64 blocks (jb), 512 thr.
// Full K per block; epilogue applies GRU nonlinearity and writes h fp32
// (in-place, owner-exclusive) + new hi/lo pair (ping-pong vs read buffer).
// ---------------------------------------------------------------------------
__global__ __launch_bounds__(512) void gru_scan(
        const short* __restrict__ A1h, const short* __restrict__ A1l, int w1, int s1,
        const short* __restrict__ A2h, const short* __restrict__ A2l, int s2,
        const short* __restrict__ Wh, const short* __restrict__ Wl, int KP, int NCH,
        const float* __restrict__ bp,
        float* __restrict__ hf, short* __restrict__ hoh, short* __restrict__ hol) {
    __shared__ short Ash[4][257][8];
    __shared__ short Asl[4][257][8];
    __shared__ short Bsh[4][65][8];
    __shared__ short Bsl[4][65][8];
    const int tid = threadIdx.x;
    const int jb = blockIdx.x;
    const int n0 = jb * 64;
    const int lane = tid & 63, wv = tid >> 6;
    const int fr = lane & 15, kg = lane >> 4;
    const int rq = kg * 4;
    const int ar = tid >> 2, akg = tid & 3;          // A loader rows ar, ar+128
    const int br = (tid & 255) >> 2, bkg = tid & 3;  // B loader
    f32x4 acc[2][4];
    #pragma unroll
    for (int i = 0; i < 2; ++i)
        #pragma unroll
        for (int j = 0; j < 4; ++j) acc[i][j] = (f32x4){0.f, 0.f, 0.f, 0.f};

    short8v rA0h, rA0l, rA1h, rA1l, rB;
    auto loadA = [&](int c) {
        int kglob = c * 32;
        const short *ph, *pl; int st, ko;
        if (kglob < w1) { ph = A1h; pl = A1l; st = s1; ko = kglob; }
        else            { ph = A2h; pl = A2l; st = s2; ko = kglob - w1; }
        size_t o1 = (size_t)ar * st + ko + akg * 8;
        size_t o2 = (size_t)(ar + 128) * st + ko + akg * 8;
        rA0h = *(const short8v*)(ph + o1); rA0l = *(const short8v*)(pl + o1);
        rA1h = *(const short8v*)(ph + o2); rA1l = *(const short8v*)(pl + o2);
    };
    auto loadB = [&](int c) {
        size_t o = (size_t)(n0 + br) * KP + c * 32 + bkg * 8;
        rB = (tid < 256) ? *(const short8v*)(Wh + o) : *(const short8v*)(Wl + o);
    };

    loadA(0); loadB(0);
    for (int c = 0; c < NCH; ++c) {
        __syncthreads();
        *(short8v*)&Ash[akg][ar][0]       = rA0h;
        *(short8v*)&Asl[akg][ar][0]       = rA0l;
        *(short8v*)&Ash[akg][ar + 128][0] = rA1h;
        *(short8v*)&Asl[akg][ar + 128][0] = rA1l;
        if (tid < 256) *(short8v*)&Bsh[bkg][br][0] = rB;
        else           *(short8v*)&Bsl[bkg][br][0] = rB;
        if (c + 1 < NCH) { loadA(c + 1); loadB(c + 1); }
        __syncthreads();
        short8v ah0 = *(const short8v*)&Ash[kg][wv * 32 + fr][0];
        short8v ah1 = *(const short8v*)&Ash[kg][wv * 32 + 16 + fr][0];
        short8v al0 = *(const short8v*)&Asl[kg][wv * 32 + fr][0];
        short8v al1 = *(const short8v*)&Asl[kg][wv * 32 + 16 + fr][0];
        #pragma unroll
        for (int nf = 0; nf < 4; ++nf) {
            short8v bh = *(const short8v*)&Bsh[kg][nf * 16 + fr][0];
            short8v bl = *(const short8v*)&Bsl[kg][nf * 16 + fr][0];
            acc[0][nf] = __builtin_amdgcn_mfma_f32_16x16x32_bf16(ah0, bh, acc[0][nf], 0, 0, 0);
            acc[0][nf] = __builtin_amdgcn_mfma_f32_16x16x32_bf16(ah0, bl, acc[0][nf], 0, 0, 0);
            acc[0][nf] = __builtin_amdgcn_mfma_f32_16x16x32_bf16(al0, bh, acc[0][nf], 0, 0, 0);
            acc[1][nf] = __builtin_amdgcn_mfma_f32_16x16x32_bf16(ah1, bh, acc[1][nf], 0, 0, 0);
            acc[1][nf] = __builtin_amdgcn_mfma_f32_16x16x32_bf16(ah1, bl, acc[1][nf], 0, 0, 0);
            acc[1][nf] = __builtin_amdgcn_mfma_f32_16x16x32_bf16(al1, bh, acc[1][nf], 0, 0, 0);
        }
        __syncthreads();
    }

    // epilogue: GRU nonlinearity, owner-exclusive h update
    const int j = jb * 16 + fr;
    const float br_ = bp[j], bz = bp[HN + j], bin = bp[2 * HN + j], bhn = bp[3 * HN + j];
    #pragma unroll
    for (int mi = 0; mi < 2; ++mi) {
        #pragma unroll
        for (int q = 0; q < 4; ++q) {
            int m = wv * 32 + mi * 16 + rq + q;
            float r = 1.f / (1.f + expf(-(acc[mi][0][q] + br_)));
            float z = 1.f / (1.f + expf(-(acc[mi][1][q] + bz)));
            float n = tanhf(acc[mi][2][q] + bin + r * (acc[mi][3][q] + bhn));
            size_t off = (size_t)m * HN + j;
            float hp = hf[off];
            float hv = (1.f - z) * n + z * hp;
            hf[off] = hv;
            short hh, ll; fsplit(hv, hh, ll);
            hoh[off] = hh; hol[off] = ll;
        }
    }
}

// ---------------------------------------------------------------------------
// Split-bf16 MFMA GEMM (general, 32x64 tile) — encoder + decoder smalls.
// EPI: 0 bias->f32 | 1 bias->pair | 2 relu(v+bias)+addm->pair | 3 relu->f32
// ---------------------------------------------------------------------------
template<int EPI>
__global__ __launch_bounds__(256) void mgemm(
        const float* __restrict__ A0, int a0w, int a0s,
        const short* __restrict__ A1h, const short* __restrict__ A1l, int a1w, int a1s,
        const short* __restrict__ A2h, const short* __restrict__ A2l, int a2w, int a2s,
        const short* __restrict__ Bh, const short* __restrict__ Bl, int KP,
        const float* __restrict__ bias, const float* __restrict__ addm,
        float* __restrict__ Cf, short* __restrict__ Cbh, short* __restrict__ Cbl,
        int N) {
    __shared__ short Ash[32][40];
    __shared__ short Asl[32][40];
    __shared__ short Bsh[64][40];
    __shared__ short Bsl[64][40];
    const int tid = threadIdx.x;
    const int m0 = blockIdx.x * 32, n0 = blockIdx.y * 64;
    const int ra = tid >> 3, ka = (tid & 7) * 4;
    const int rb = tid >> 2, kb = (tid & 3) * 8;
    const int lane = tid & 63, wv = tid >> 6;
    const int wm = (wv & 1) * 16, wn = (wv >> 1) * 32;
    const int fr = lane & 15, fo = (lane >> 4) * 8;
    const int a01 = a0w + a1w, a012 = a01 + a2w;
    f32x4 acc0 = {0.f, 0.f, 0.f, 0.f}, acc1 = {0.f, 0.f, 0.f, 0.f};

    auto ldA = [&](int k, short& hh, short& ll) {
        if (k < a0w) {
            fsplit(A0[(size_t)(m0 + ra) * a0s + k], hh, ll);
        } else if (k < a01) {
            size_t o = (size_t)(m0 + ra) * a1s + (k - a0w);
            hh = A1h[o]; ll = A1l[o];
        } else if (k < a012) {
            size_t o = (size_t)(m0 + ra) * a2s + (k - a01);
            hh = A2h[o]; ll = A2l[o];
        } else { hh = 0; ll = 0; }
    };

    short avh[4], avl[4];
    short8v bvh, bvl;
    #pragma unroll
    for (int j = 0; j < 4; ++j) ldA(ka + j, avh[j], avl[j]);
    bvh = *(const short8v*)(Bh + (size_t)(n0 + rb) * KP + kb);
    bvl = *(const short8v*)(Bl + (size_t)(n0 + rb) * KP + kb);

    for (int k0 = 0; k0 < KP; k0 += 32) {
        #pragma unroll
        for (int j = 0; j < 4; ++j) { Ash[ra][ka + j] = avh[j]; Asl[ra][ka + j] = avl[j]; }
        *(short8v*)&Bsh[rb][kb] = bvh;
        *(short8v*)&Bsl[rb][kb] = bvl;
        int kn = k0 + 32;
        if (kn < KP) {
            #pragma unroll
            for (int j = 0; j < 4; ++j) ldA(kn + ka + j, avh[j], avl[j]);
            bvh = *(const short8v*)(Bh + (size_t)(n0 + rb) * KP + kn + kb);
            bvl = *(const short8v*)(Bl + (size_t)(n0 + rb) * KP + kn + kb);
        }
        __syncthreads();
        short8v ah  = *(const short8v*)&Ash[wm + fr][fo];
        short8v al  = *(const short8v*)&Asl[wm + fr][fo];
        short8v b0h = *(const short8v*)&Bsh[wn + fr][fo];
        short8v b0l = *(const short8v*)&Bsl[wn + fr][fo];
        short8v b1h = *(const short8v*)&Bsh[wn + 16 + fr][fo];
        short8v b1l = *(const short8v*)&Bsl[wn + 16 + fr][fo];
        acc0 = __builtin_amdgcn_mfma_f32_16x16x32_bf16(ah, b0h, acc0, 0, 0, 0);
        acc0 = __builtin_amdgcn_mfma_f32_16x16x32_bf16(ah, b0l, acc0, 0, 0, 0);
        acc0 = __builtin_amdgcn_mfma_f32_16x16x32_bf16(al, b0h, acc0, 0, 0, 0);
        acc1 = __builtin_amdgcn_mfma_f32_16x16x32_bf16(ah, b1h, acc1, 0, 0, 0);
        acc1 = __builtin_amdgcn_mfma_f32_16x16x32_bf16(ah, b1l, acc1, 0, 0, 0);
        acc1 = __builtin_amdgcn_mfma_f32_16x16x32_bf16(al, b1h, acc1, 0, 0, 0);
        __syncthreads();
    }

    const int rq = (lane >> 4) * 4;
    #pragma unroll
    for (int f = 0; f < 2; ++f) {
        f32x4 acc = f ? acc1 : acc0;
        int n = n0 + wn + f * 16 + fr;
        float bb = bias[n];
        #pragma unroll
        for (int q = 0; q < 4; ++q) {
            int m = m0 + wm + rq + q;
            size_t off = (size_t)m * N + n;
            float v = acc[q] + bb;
            if (EPI == 0) {
                Cf[off] = v;
            } else if (EPI == 1) {
                short hh, ll; fsplit(v, hh, ll);
                Cbh[off] = hh; Cbl[off] = ll;
            } else if (EPI == 2) {
                v = fmaxf(v, 0.f) + addm[off];
                short hh, ll; fsplit(v, hh, ll);
                Cbh[off] = hh; Cbl[off] = ll;
            } else {
                Cf[off] = fmaxf(v, 0.f);
            }
        }
    }
}

// ---------------------------------------------------------------------------
// attention (one block per (batch, head)); accumulates mean_t(o) into obar
// ---------------------------------------------------------------------------
__global__ __launch_bounds__(256) void attn_kernel(const float* __restrict__ qkv,
                                                   float* __restrict__ obar, int b0) {
    __shared__ float Qs[FN][DH];
    __shared__ float Ks[FN][DH];
    __shared__ float Ss[FN][62];
    const int bl = blockIdx.x, h = blockIdx.y;
    const float* base = qkv + (size_t)bl * FN * 3 * HN + h * DH;
    for (int i = threadIdx.x; i < FN * DH; i += 256) {
        int t = i >> 8, d = i & 255;
        Qs[t][d] = base[(size_t)t * 3 * HN + d];
        Ks[t][d] = base[(size_t)t * 3 * HN + HN + d];
    }
    __syncthreads();
    for (int p = threadIdx.x; p < FN * FN; p += 256) {
        int qi = p / FN, kj = p - qi * FN;
        const float4* qp = (const float4*)&Qs[qi][0];
        const float4* kp = (const float4*)&Ks[kj][0];
        float s = 0.f;
        #pragma unroll
        for (int c = 0; c < DH / 4; ++c) {
            float4 a = qp[c], b = kp[c];
            s += a.x * b.x + a.y * b.y + a.z * b.z + a.w * b.w;
        }
        Ss[qi][kj] = s * 0.0625f;
    }
    __syncthreads();
    if (threadIdx.x < FN) {
        int qi = threadIdx.x;
        float mx = -1e30f;
        for (int j = 0; j < FN; ++j) mx = fmaxf(mx, Ss[qi][j]);
        float sm = 0.f;
        for (int j = 0; j < FN; ++j) { float e = expf(Ss[qi][j] - mx); Ss[qi][j] = e; sm += e; }
        float inv = 1.f / sm;
        for (int j = 0; j < FN; ++j) Ss[qi][j] *= inv;
    }
    __syncthreads();
    float* Vs = &Qs[0][0];
    for (int i = threadIdx.x; i < FN * DH; i += 256) {
        int t = i >> 8, d = i & 255;
        Vs[t * DH + d] = base[(size_t)t * 3 * HN + 2 * HN + d];
    }
    __syncthreads();
    int d = threadIdx.x;
    float accum = 0.f;
    for (int qi = 0; qi < FN; ++qi) {
        float o = 0.f;
        for (int j = 0; j < FN; ++j) o += Ss[qi][j] * Vs[j * DH + d];
        accum += o;
    }
    obar[(size_t)(b0 + bl) * HN + h * DH + d] = accum * (1.f / (float)FN);
}

// ---------------------------------------------------------------------------
// decoder prep / fused spl2+rot  (x kept as split pair [256][XWP])
// ---------------------------------------------------------------------------
__global__ __launch_bounds__(128) void prep_kernel(const float* __restrict__ poses,
                                                   float* __restrict__ sixd,
                                                   short* __restrict__ xdh,
                                                   short* __restrict__ xdl) {
    int b = blockIdx.x;
    const float* src = poses + ((size_t)b * TT + (TSEED - 1)) * DN;
    for (int d = threadIdx.x; d < DN; d += 128) {
        short hh, ll; fsplit(src[d], hh, ll);
        xdh[b * XWP + d] = hh; xdl[b * XWP + d] = ll;
    }
    for (int p = threadIdx.x; p < JN * 6; p += 128) {
        int j = p / 6, c = p - j * 6;
        int i = (c < 3) ? c : (c - 3);
        int col = (c < 3) ? 0 : 1;
        sixd[b * JN * 6 + p] = src[j * 9 + i * 3 + col];
    }
}

__global__ __launch_bounds__(128) void spl2rot_kernel(const float* __restrict__ z1,
                                                      const float* __restrict__ w2,
                                                      const float* __restrict__ b2,
                                                      float* __restrict__ sixd,
                                                      float* __restrict__ out, int t,
                                                      short* __restrict__ xdh,
                                                      short* __restrict__ xdl) {
    int b = blockIdx.x, p = threadIdx.x;
    if (p < JN * 6) {
        int j = p / 6, o = p - j * 6;
        const float* z = z1 + (size_t)b * (JN * 128) + j * 128;
        const float* wv = w2 + (j * 6 + o) * 128;
        float s = b2[j * 6 + o];
        #pragma unroll 4
        for (int k = 0; k < 128; ++k) s += z[k] * wv[k];
        float nv = sixd[b * JN * 6 + p] + s;
        sixd[b * JN * 6 + p] = nv;
        out[((size_t)b * PREDN + t) * (JN * 6) + p] = nv;
    }
    __syncthreads();
    if (p < JN) {
        int j = p;
        const float* v = sixd + b * JN * 6 + j * 6;
        float a1x = v[0], a1y = v[2], a1z = v[4];
        float a2x = v[1], a2y = v[3], a2z = v[5];
        float n1 = fmaxf(sqrtf(a1x * a1x + a1y * a1y + a1z * a1z), 1e-12f);
        float b1x = a1x / n1, b1y = a1y / n1, b1z = a1z / n1;
        float dt = b1x * a2x + b1y * a2y + b1z * a2z;
        float ox = a2x - dt * b1x, oy = a2y - dt * b1y, oz = a2z - dt * b1z;
        float n2 = fmaxf(sqrtf(ox * ox + oy * oy + oz * oz), 1e-12f);
        float b2x = ox / n2, b2y = oy / n2, b2z = oz / n2;
        float b3x = b1y * b2z - b1z * b2y;
        float b3y = b1z * b2x - b1x * b2z;
        float b3z = b1x * b2y - b1y * b2x;
        float r9[9] = {b1x, b2x, b3x, b1y, b2y, b3y, b1z, b2z, b3z};
        short* oh = xdh + (size_t)b * XWP + j * 9;
        short* ol = xdl + (size_t)b * XWP + j * 9;
        #pragma unroll
        for (int q = 0; q < 9; ++q) {
            short hh, ll; fsplit(r9[q], hh, ll);
            oh[q] = hh; ol[q] = ll;
        }
    }
}

// ---------------------------------------------------------------------------
extern "C" void kernel_launch(void* const* d_in, const int* in_sizes, int n_in,
                              void* d_out, int out_size, void* d_ws, size_t ws_size,
                              hipStream_t stream) {
    const float* poses  = (const float*)d_in[0];
    const float* freq_w = (const float*)d_in[1];
    const float* freq_b = (const float*)d_in[2];
    const float* ain_w  = (const float*)d_in[3];
    const float* ain_b  = (const float*)d_in[4];
    const float* aout_w = (const float*)d_in[5];
    const float* aout_b = (const float*)d_in[6];
    const float* wih0   = (const float*)d_in[7];
    const float* whh0   = (const float*)d_in[8];
    const float* bih0   = (const float*)d_in[9];
    const float* bhh0   = (const float*)d_in[10];
    const float* wih1   = (const float*)d_in[11];
    const float* whh1   = (const float*)d_in[12];
    const float* bih1   = (const float*)d_in[13];
    const float* bhh1   = (const float*)d_in[14];
    const float* pre_w  = (const float*)d_in[15];
    const float* pre_b  = (const float*)d_in[16];
    const float* spl_w1 = (const float*)d_in[17];
    const float* spl_b1 = (const float*)d_in[18];
    const float* spl_w2 = (const float*)d_in[19];
    const float* spl_b2 = (const float*)d_in[20];
    float* out = (float*)d_out;

    char* p = (char*)d_ws;
    auto alloc = [&](size_t bytes) { void* r = p; p += (bytes + 255) & ~(size_t)255; return r; };
    short* W0h    = (short*)alloc((size_t)4096 * KP0 * 2);
    short* W0l    = (short*)alloc((size_t)4096 * KP0 * 2);
    short* W1h    = (short*)alloc((size_t)4096 * KP1 * 2);
    short* W1l    = (short*)alloc((size_t)4096 * KP1 * 2);
    float* b0p    = (float*)alloc(4096 * 4);
    float* b1p    = (float*)alloc(4096 * 4);
    short* freqh  = (short*)alloc((size_t)1024 * KPF * 2);
    short* freql  = (short*)alloc((size_t)1024 * KPF * 2);
    short* ainh   = (short*)alloc((size_t)3072 * 1024 * 2);
    short* ainl   = (short*)alloc((size_t)3072 * 1024 * 2);
    short* aouth  = (short*)alloc((size_t)1024 * 1024 * 2);
    short* aoutl  = (short*)alloc((size_t)1024 * 1024 * 2);
    short* preh   = (short*)alloc((size_t)1024 * 1024 * 2);
    short* prel   = (short*)alloc((size_t)1024 * 1024 * 2);
    short* spl1h  = (short*)alloc((size_t)1920 * 1024 * 2);
    short* spl1l  = (short*)alloc((size_t)1920 * 1024 * 2);
    short* Xh     = (short*)alloc((size_t)TSEED * BB * XWP * 2);
    short* Xl     = (short*)alloc((size_t)TSEED * BB * XWP * 2);
    float* cosm   = (float*)alloc(FN * TSEED * 4);
    float* freqf  = (float*)alloc((size_t)BB * FN * DN * 4);
    short* feath  = (short*)alloc((size_t)RCH * HN * 2);
    short* featl  = (short*)alloc((size_t)RCH * HN * 2);
    float* qkvc   = (float*)alloc((size_t)RCH * 3 * HN * 4);
    float* obar   = (float*)alloc((size_t)BB * HN * 4);
    float* mctx   = (float*)alloc((size_t)BB * HN * 4);
    float* h0     = (float*)alloc((size_t)BB * HN * 4);
    float* h1     = (float*)alloc((size_t)BB * HN * 4);
    short* h0pA   = (short*)alloc((size_t)BB * HN * 2);
    short* h0lA   = (short*)alloc((size_t)BB * HN * 2);
    short* h0pB   = (short*)alloc((size_t)BB * HN * 2);
    short* h0lB   = (short*)alloc((size_t)BB * HN * 2);
    short* h1pA   = (short*)alloc((size_t)BB * HN * 2);
    short* h1lA   = (short*)alloc((size_t)BB * HN * 2);
    short* h1pB   = (short*)alloc((size_t)BB * HN * 2);
    short* h1lB   = (short*)alloc((size_t)BB * HN * 2);
    short* hidh   = (short*)alloc((size_t)BB * HN * 2);
    short* hidl   = (short*)alloc((size_t)BB * HN * 2);
    float* z1     = (float*)alloc((size_t)BB * JN * 128 * 4);
    float* sixd   = (float*)alloc((size_t)BB * JN * 6 * 4);
    short* xdh    = (short*)alloc((size_t)BB * XWP * 2);
    short* xdl    = (short*)alloc((size_t)BB * XWP * 2);

    // ---- prepack (every call; graph-safe) ----
    pack_gruw_i<<<4096, 256, 0, stream>>>(wih0, whh0, DN, XWP, KP0, W0h, W0l);
    pack_gruw_i<<<4096, 256, 0, stream>>>(wih1, whh1, HN, HN, KP1, W1h, W1l);
    pack_grub<<<16, 256, 0, stream>>>(bih0, bhh0, b0p);
    pack_grub<<<16, 256, 0, stream>>>(bih1, bhh1, b1p);
    castw<<<1024, 256, 0, stream>>>(freq_w, freqh, freql, DN, KPF);
    castw<<<3072, 256, 0, stream>>>(ain_w, ainh, ainl, HN, HN);
    castw<<<1024, 256, 0, stream>>>(aout_w, aouth, aoutl, HN, HN);
    castw<<<1024, 256, 0, stream>>>(pre_w, preh, prel, HN, HN);
    castw<<<1920, 256, 0, stream>>>(spl_w1, spl1h, spl1l, HN, HN);
    pack_x<<<TSEED, 256, 0, stream>>>(poses, Xh, Xl);

    // ---- encoder ----
    cos_kernel<<<FN, 128, 0, stream>>>(cosm);
    dft_kernel<<<BB, 256, 0, stream>>>(poses, cosm, freqf);
    for (int bc = 0; bc < BB / BCH; ++bc) {
        mgemm<1><<<dim3(RCH / 32, HN / 64), 256, 0, stream>>>(
            freqf + (size_t)bc * RCH * DN, DN, DN,
            nullptr, nullptr, 0, 0, nullptr, nullptr, 0, 0,
            freqh, freql, KPF, freq_b, nullptr, nullptr, feath, featl, HN);
        mgemm<0><<<dim3(RCH / 32, 3 * HN / 64), 256, 0, stream>>>(
            nullptr, 0, 0, feath, featl, HN, HN, nullptr, nullptr, 0, 0,
            ainh, ainl, HN, ain_b, nullptr, qkvc, nullptr, nullptr, 3 * HN);
        attn_kernel<<<dim3(BCH, 4), 256, 0, stream>>>(qkvc, obar, bc * BCH);
    }
    mgemm<0><<<dim3(BB / 32, HN / 64), 256, 0, stream>>>(
        obar, HN, HN, nullptr, nullptr, 0, 0, nullptr, nullptr, 0, 0,
        aouth, aoutl, HN, aout_b, nullptr, mctx, nullptr, nullptr, HN);

    // ---- GRU scan: 2 fused dispatches per step, ping-pong h pairs ----
    hipMemsetAsync(h0, 0, (size_t)BB * HN * 4, stream);
    hipMemsetAsync(h1, 0, (size_t)BB * HN * 4, stream);
    hipMemsetAsync(h0pA, 0, (size_t)BB * HN * 2, stream);
    hipMemsetAsync(h0lA, 0, (size_t)BB * HN * 2, stream);
    hipMemsetAsync(h1pA, 0, (size_t)BB * HN * 2, stream);
    hipMemsetAsync(h1lA, 0, (size_t)BB * HN * 2, stream);
    short *h0rh = h0pA, *h0rl = h0lA, *h0wh = h0pB, *h0wl = h0lB;
    short *h1rh = h1pA, *h1rl = h1lA, *h1wh = h1pB, *h1wl = h1lB;
    short* tmp;
    for (int t = 0; t < TSEED; ++t) {
        gru_scan<<<64, 512, 0, stream>>>(
            Xh + (size_t)t * BB * XWP, Xl + (size_t)t * BB * XWP, XWP, XWP,
            h0rh, h0rl, HN, W0h, W0l, KP0, KP0 / 32, b0p, h0, h0wh, h0wl);
        tmp = h0rh; h0rh = h0wh; h0wh = tmp; tmp = h0rl; h0rl = h0wl; h0wl = tmp;
        gru_scan<<<64, 512, 0, stream>>>(
            h0rh, h0rl, HN, HN, h1rh, h1rl, HN,
            W1h, W1l, KP1, KP1 / 32, b1p, h1, h1wh, h1wl);
        tmp = h1rh; h1rh = h1wh; h1wh = tmp; tmp = h1rl; h1rl = h1wl; h1wl = tmp;
    }

    // ---- decoder ----
    hipMemsetAsync(xdh, 0, (size_t)BB * XWP * 2, stream);
    hipMemsetAsync(xdl, 0, (size_t)BB * XWP * 2, stream);
    prep_kernel<<<BB, 128, 0, stream>>>(poses, sixd, xdh, xdl);
    for (int t = 0; t < PREDN; ++t) {
        gru_scan<<<64, 512, 0, stream>>>(
            xdh, xdl, XWP, XWP, h0rh, h0rl, HN,
            W0h, W0l, KP0, KP0 / 32, b0p, h0, h0wh, h0wl);
        tmp = h0rh; h0rh = h0wh; h0wh = tmp; tmp = h0rl; h0rl = h0wl; h0wl = tmp;
        gru_scan<<<64, 512, 0, stream>>>(
            h0rh, h0rl, HN, HN, h1rh, h1rl, HN,
            W1h, W1l, KP1, KP1 / 32, b1p, h1, h1wh, h1wl);
        tmp = h1rh; h1rh = h1wh; h1wh = tmp; tmp = h1rl; h1rl = h1wl; h1wl = tmp;
        mgemm<2><<<dim3(BB / 32, HN / 64), 256, 0, stream>>>(
            nullptr, 0, 0, h1rh, h1rl, HN, HN, nullptr, nullptr, 0, 0,
            preh, prel, HN, pre_b, mctx, nullptr, hidh, hidl, HN);
        mgemm<3><<<dim3(BB / 32, 1920 / 64), 256, 0, stream>>>(
            nullptr, 0, 0, hidh, hidl, HN, HN, nullptr, nullptr, 0, 0,
            spl1h, spl1l, HN, spl_b1, nullptr, z1, nullptr, nullptr, 1920);
        spl2rot_kernel<<<BB, 128, 0, stream>>>(z1, spl_w2, spl_b2, sixd, out, t, xdh, xdl);
    }
}

// Round 6
// 13750.516 us; speedup vs baseline: 1.5698x; 1.5698x over previous
//
#include <hip/hip_runtime.h>

#define BB     256
#define TSEED  120
#define PREDN  24
#define JN     15
#define HN     1024
#define DN     135
#define FN     61
#define TT     144
#define DH     256
#define BCH    32
#define RCH    (BCH*FN)   // 1952 rows per encoder chunk
#define KPF    160        // 135 padded for freq weights
#define XWP    160        // padded x width for GRU layer0
#define KP0    (XWP+HN)   // 1184
#define KP1    (2*HN)     // 2048

typedef __attribute__((ext_vector_type(8))) short short8v;
typedef __attribute__((ext_vector_type(4))) float f32x4;

__device__ __forceinline__ short f2b(float f) {
    union { float f; unsigned u; } v; v.f = f;
    unsigned r = (v.u + 0x7FFFu + ((v.u >> 16) & 1u)) >> 16;
    return (short)r;
}
__device__ __forceinline__ float b2f(short h) {
    union { unsigned u; float f; } x; x.u = ((unsigned)(unsigned short)h) << 16; return x.f;
}
__device__ __forceinline__ void fsplit(float v, short& h, short& l) {
    h = f2b(v); l = f2b(v - b2f(h));
}

// ---------------------------------------------------------------------------
// prepack: GRU fused weight, gate-INTERLEAVED packed rows:
//   n' = jb*64 + g*16 + jj ; g: 0=r 1=z 2=in 3=hn
// ---------------------------------------------------------------------------
__global__ __launch_bounds__(256) void pack_gruw_i(const float* __restrict__ wih,
                                                   const float* __restrict__ whh,
                                                   int KX, int XW, int KP,
                                                   short* __restrict__ Wh,
                                                   short* __restrict__ Wl) {
    int np = blockIdx.x;
    int jb = np >> 6, g = (np >> 4) & 3, jj = np & 15;
    int j = jb * 16 + jj;
    for (int k = threadIdx.x; k < KP; k += 256) {
        float v = 0.f;
        if (k < KX) {
            if (g < 3) v = wih[(size_t)(g * HN + j) * KX + k];
        } else if (k >= XW) {
            int kk = k - XW;
            if (g == 0)      v = whh[(size_t)j * HN + kk];
            else if (g == 1) v = whh[(size_t)(HN + j) * HN + kk];
            else if (g == 3) v = whh[(size_t)(2 * HN + j) * HN + kk];
        }
        short hh, ll; fsplit(v, hh, ll);
        Wh[(size_t)np * KP + k] = hh;
        Wl[(size_t)np * KP + k] = ll;
    }
}

__global__ __launch_bounds__(256) void pack_grub(const float* __restrict__ bih,
                                                 const float* __restrict__ bhh,
                                                 float* __restrict__ bp) {
    int n = blockIdx.x * 256 + threadIdx.x;
    if (n < 4 * HN) {
        int g = n >> 10, j = n & 1023;
        float v;
        if (g == 0)      v = bih[j] + bhh[j];
        else if (g == 1) v = bih[HN + j] + bhh[HN + j];
        else if (g == 2) v = bih[2 * HN + j];
        else             v = bhh[2 * HN + j];
        bp[n] = v;
    }
}

__global__ __launch_bounds__(256) void castw(const float* __restrict__ w,
                                             short* __restrict__ oh,
                                             short* __restrict__ ol, int K, int KP) {
    int n = blockIdx.x;
    for (int k = threadIdx.x; k < KP; k += 256) {
        float v = (k < K) ? w[(size_t)n * K + k] : 0.f;
        short hh, ll; fsplit(v, hh, ll);
        oh[(size_t)n * KP + k] = hh;
        ol[(size_t)n * KP + k] = ll;
    }
}

__global__ __launch_bounds__(256) void pack_x(const float* __restrict__ poses,
                                              short* __restrict__ Xh,
                                              short* __restrict__ Xl) {
    int t = blockIdx.x;
    short* oh = Xh + (size_t)t * BB * XWP;
    short* ol = Xl + (size_t)t * BB * XWP;
    for (int i = threadIdx.x; i < BB * XWP; i += 256) {
        int b = i / XWP, k = i - b * XWP;
        float v = (k < DN) ? poses[((size_t)b * TT + t) * DN + k] : 0.f;
        short hh, ll; fsplit(v, hh, ll);
        oh[i] = hh; ol[i] = ll;
    }
}

// ---------------------------------------------------------------------------
// cos table + DFT (real part of rfft)
// ---------------------------------------------------------------------------
__global__ __launch_bounds__(128) void cos_kernel(float* __restrict__ cosm) {
    int f = blockIdx.x, t = threadIdx.x;
    if (t < TSEED) {
        int ft = (f * t) % TSEED;
        cosm[f * TSEED + t] = cosf((float)ft * (6.283185307179586f / (float)TSEED));
    }
}

__global__ __launch_bounds__(256) void dft_kernel(const float* __restrict__ poses,
                                                  const float* __restrict__ cosm,
                                                  float* __restrict__ freq) {
    __shared__ float cs[FN * TSEED];
    for (int i = threadIdx.x; i < FN * TSEED; i += 256) cs[i] = cosm[i];
    __syncthreads();
    const float* xp = poses + (size_t)blockIdx.x * TT * DN;
    float* fp = freq + (size_t)blockIdx.x * FN * DN;
    for (int o = threadIdx.x; o < FN * DN; o += 256) {
        int f = o / DN, d = o - f * DN;
        const float* cf = &cs[f * TSEED];
        float s = 0.f;
        #pragma unroll 4
        for (int t = 0; t < TSEED; ++t) s += xp[t * DN + d] * cf[t];
        fp[o] = s;
    }
}

// ---------------------------------------------------------------------------
// GRU scan step.  Grid (4 m-blocks, 64 jb), 256 threads = 4 waves.
// Block = 64 batch rows x 64 packed gate-cols; wave = 32x32 (acc[2][2]).
// LDS tiles [row][40] (pad) -> <=2-way bank conflicts on b128 ops.
// Epilogue: gates staged via LDS gbuf (reuses tile LDS), GRU nonlinearity,
// owner-exclusive h update (fp32 master + bf16 hi/lo ping-pong pair).
// ---------------------------------------------------------------------------
__global__ __launch_bounds__(256) void gru_scan(
        const short* __restrict__ A1h, const short* __restrict__ A1l, int w1, int s1,
        const short* __restrict__ A2h, const short* __restrict__ A2l, int s2,
        const short* __restrict__ Wh, const short* __restrict__ Wl, int KP, int NCH,
        const float* __restrict__ bp,
        float* __restrict__ hf, short* __restrict__ hoh, short* __restrict__ hol) {
    __shared__ __align__(16) char smem[20480];
    short* Ash = (short*)smem;          // [64][40]
    short* Asl = Ash + 64 * 40;
    short* Bsh = Asl + 64 * 40;
    short* Bsl = Bsh + 64 * 40;
    float* gbuf = (float*)smem;         // [64][65] floats (16640 B)

    const int tid = threadIdx.x;
    const int m0 = blockIdx.x * 64;
    const int jb = blockIdx.y;
    const int n0 = jb * 64;
    const int lane = tid & 63, wv = tid >> 6;
    const int mslot = wv & 1, nslot = wv >> 1;
    const int fr = lane & 15, kg = lane >> 4;
    const int rq = kg * 4;
    const int ldr = tid >> 2, ldk = tid & 3;   // loader: row 0..63, k-subgroup
    f32x4 acc[2][2];
    acc[0][0] = (f32x4){0.f,0.f,0.f,0.f}; acc[0][1] = (f32x4){0.f,0.f,0.f,0.f};
    acc[1][0] = (f32x4){0.f,0.f,0.f,0.f}; acc[1][1] = (f32x4){0.f,0.f,0.f,0.f};

    short8v rAh, rAl, rBh, rBl;
    auto loadA = [&](int c) {
        int kglob = c * 32;
        const short *ph, *pl; int st, ko;
        if (kglob < w1) { ph = A1h; pl = A1l; st = s1; ko = kglob; }
        else            { ph = A2h; pl = A2l; st = s2; ko = kglob - w1; }
        size_t o = (size_t)(m0 + ldr) * st + ko + ldk * 8;
        rAh = *(const short8v*)(ph + o); rAl = *(const short8v*)(pl + o);
    };
    auto loadB = [&](int c) {
        size_t o = (size_t)(n0 + ldr) * KP + c * 32 + ldk * 8;
        rBh = *(const short8v*)(Wh + o); rBl = *(const short8v*)(Wl + o);
    };

    loadA(0); loadB(0);
    for (int c = 0; c < NCH; ++c) {
        __syncthreads();
        *(short8v*)&Ash[ldr * 40 + ldk * 8] = rAh;
        *(short8v*)&Asl[ldr * 40 + ldk * 8] = rAl;
        *(short8v*)&Bsh[ldr * 40 + ldk * 8] = rBh;
        *(short8v*)&Bsl[ldr * 40 + ldk * 8] = rBl;
        if (c + 1 < NCH) { loadA(c + 1); loadB(c + 1); }
        __syncthreads();
        short8v ah0 = *(const short8v*)&Ash[(mslot * 32 + fr) * 40 + kg * 8];
        short8v ah1 = *(const short8v*)&Ash[(mslot * 32 + 16 + fr) * 40 + kg * 8];
        short8v al0 = *(const short8v*)&Asl[(mslot * 32 + fr) * 40 + kg * 8];
        short8v al1 = *(const short8v*)&Asl[(mslot * 32 + 16 + fr) * 40 + kg * 8];
        short8v bh0 = *(const short8v*)&Bsh[(nslot * 32 + fr) * 40 + kg * 8];
        short8v bh1 = *(const short8v*)&Bsh[(nslot * 32 + 16 + fr) * 40 + kg * 8];
        short8v bl0 = *(const short8v*)&Bsl[(nslot * 32 + fr) * 40 + kg * 8];
        short8v bl1 = *(const short8v*)&Bsl[(nslot * 32 + 16 + fr) * 40 + kg * 8];
        acc[0][0] = __builtin_amdgcn_mfma_f32_16x16x32_bf16(ah0, bh0, acc[0][0], 0, 0, 0);
        acc[0][0] = __builtin_amdgcn_mfma_f32_16x16x32_bf16(ah0, bl0, acc[0][0], 0, 0, 0);
        acc[0][0] = __builtin_amdgcn_mfma_f32_16x16x32_bf16(al0, bh0, acc[0][0], 0, 0, 0);
        acc[0][1] = __builtin_amdgcn_mfma_f32_16x16x32_bf16(ah0, bh1, acc[0][1], 0, 0, 0);
        acc[0][1] = __builtin_amdgcn_mfma_f32_16x16x32_bf16(ah0, bl1, acc[0][1], 0, 0, 0);
        acc[0][1] = __builtin_amdgcn_mfma_f32_16x16x32_bf16(al0, bh1, acc[0][1], 0, 0, 0);
        acc[1][0] = __builtin_amdgcn_mfma_f32_16x16x32_bf16(ah1, bh0, acc[1][0], 0, 0, 0);
        acc[1][0] = __builtin_amdgcn_mfma_f32_16x16x32_bf16(ah1, bl0, acc[1][0], 0, 0, 0);
        acc[1][0] = __builtin_amdgcn_mfma_f32_16x16x32_bf16(al1, bh0, acc[1][0], 0, 0, 0);
        acc[1][1] = __builtin_amdgcn_mfma_f32_16x16x32_bf16(ah1, bh1, acc[1][1], 0, 0, 0);
        acc[1][1] = __builtin_amdgcn_mfma_f32_16x16x32_bf16(ah1, bl1, acc[1][1], 0, 0, 0);
        acc[1][1] = __builtin_amdgcn_mfma_f32_16x16x32_bf16(al1, bh1, acc[1][1], 0, 0, 0);
        __syncthreads();
    }

    // stage gates to LDS: gbuf[m_local][gate*16 + jj]
    __syncthreads();
    #pragma unroll
    for (int mi = 0; mi < 2; ++mi) {
        #pragma unroll
        for (int nf = 0; nf < 2; ++nf) {
            int ml = mslot * 32 + mi * 16 + rq;
            int cn = nslot * 32 + nf * 16 + fr;
            #pragma unroll
            for (int q = 0; q < 4; ++q)
                gbuf[(ml + q) * 65 + cn] = acc[mi][nf][q];
        }
    }
    __syncthreads();

    // combine: 64 rows x 16 j outputs
    #pragma unroll
    for (int rep = 0; rep < 4; ++rep) {
        int idx = tid + rep * 256;
        int ml = idx >> 4, jj = idx & 15;
        int j = jb * 16 + jj;
        float r  = gbuf[ml * 65 + jj]       + bp[j];
        float z  = gbuf[ml * 65 + 16 + jj]  + bp[HN + j];
        float gi = gbuf[ml * 65 + 32 + jj]  + bp[2 * HN + j];
        float gh = gbuf[ml * 65 + 48 + jj]  + bp[3 * HN + j];
        r = 1.f / (1.f + expf(-r));
        z = 1.f / (1.f + expf(-z));
        float n = tanhf(gi + r * gh);
        size_t off = (size_t)(m0 + ml) * HN + j;
        float hp = hf[off];
        float hv = (1.f - z) * n + z * hp;
        hf[off] = hv;
        short hh, ll; fsplit(hv, hh, ll);
        hoh[off] = hh; hol[off] = ll;
    }
}

// ---------------------------------------------------------------------------
// Split-bf16 MFMA GEMM (general, 32x64 tile) — encoder + decoder smalls.
// EPI: 0 bias->f32 | 1 bias->pair | 2 relu(v+bias)+addm->pair | 3 relu->f32
// ---------------------------------------------------------------------------
template<int EPI>
__global__ __launch_bounds__(256) void mgemm(
        const float* __restrict__ A0, int a0w, int a0s,
        const short* __restrict__ A1h, const short* __restrict__ A1l, int a1w, int a1s,
        const short* __restrict__ A2h, const short* __restrict__ A2l, int a2w, int a2s,
        const short* __restrict__ Bh, const short* __restrict__ Bl, int KP,
        const float* __restrict__ bias, const float* __restrict__ addm,
        float* __restrict__ Cf, short* __restrict__ Cbh, short* __restrict__ Cbl,
        int N) {
    __shared__ short Ash[32][40];
    __shared__ short Asl[32][40];
    __shared__ short Bsh[64][40];
    __shared__ short Bsl[64][40];
    const int tid = threadIdx.x;
    const int m0 = blockIdx.x * 32, n0 = blockIdx.y * 64;
    const int ra = tid >> 3, ka = (tid & 7) * 4;
    const int rb = tid >> 2, kb = (tid & 3) * 8;
    const int lane = tid & 63, wv = tid >> 6;
    const int wm = (wv & 1) * 16, wn = (wv >> 1) * 32;
    const int fr = lane & 15, fo = (lane >> 4) * 8;
    const int a01 = a0w + a1w, a012 = a01 + a2w;
    f32x4 acc0 = {0.f, 0.f, 0.f, 0.f}, acc1 = {0.f, 0.f, 0.f, 0.f};

    auto ldA = [&](int k, short& hh, short& ll) {
        if (k < a0w) {
            fsplit(A0[(size_t)(m0 + ra) * a0s + k], hh, ll);
        } else if (k < a01) {
            size_t o = (size_t)(m0 + ra) * a1s + (k - a0w);
            hh = A1h[o]; ll = A1l[o];
        } else if (k < a012) {
            size_t o = (size_t)(m0 + ra) * a2s + (k - a01);
            hh = A2h[o]; ll = A2l[o];
        } else { hh = 0; ll = 0; }
    };

    short avh[4], avl[4];
    short8v bvh, bvl;
    #pragma unroll
    for (int j = 0; j < 4; ++j) ldA(ka + j, avh[j], avl[j]);
    bvh = *(const short8v*)(Bh + (size_t)(n0 + rb) * KP + kb);
    bvl = *(const short8v*)(Bl + (size_t)(n0 + rb) * KP + kb);

    for (int k0 = 0; k0 < KP; k0 += 32) {
        #pragma unroll
        for (int j = 0; j < 4; ++j) { Ash[ra][ka + j] = avh[j]; Asl[ra][ka + j] = avl[j]; }
        *(short8v*)&Bsh[rb][kb] = bvh;
        *(short8v*)&Bsl[rb][kb] = bvl;
        int kn = k0 + 32;
        if (kn < KP) {
            #pragma unroll
            for (int j = 0; j < 4; ++j) ldA(kn + ka + j, avh[j], avl[j]);
            bvh = *(const short8v*)(Bh + (size_t)(n0 + rb) * KP + kn + kb);
            bvl = *(const short8v*)(Bl + (size_t)(n0 + rb) * KP + kn + kb);
        }
        __syncthreads();
        short8v ah  = *(const short8v*)&Ash[wm + fr][fo];
        short8v al  = *(const short8v*)&Asl[wm + fr][fo];
        short8v b0h = *(const short8v*)&Bsh[wn + fr][fo];
        short8v b0l = *(const short8v*)&Bsl[wn + fr][fo];
        short8v b1h = *(const short8v*)&Bsh[wn + 16 + fr][fo];
        short8v b1l = *(const short8v*)&Bsl[wn + 16 + fr][fo];
        acc0 = __builtin_amdgcn_mfma_f32_16x16x32_bf16(ah, b0h, acc0, 0, 0, 0);
        acc0 = __builtin_amdgcn_mfma_f32_16x16x32_bf16(ah, b0l, acc0, 0, 0, 0);
        acc0 = __builtin_amdgcn_mfma_f32_16x16x32_bf16(al, b0h, acc0, 0, 0, 0);
        acc1 = __builtin_amdgcn_mfma_f32_16x16x32_bf16(ah, b1h, acc1, 0, 0, 0);
        acc1 = __builtin_amdgcn_mfma_f32_16x16x32_bf16(ah, b1l, acc1, 0, 0, 0);
        acc1 = __builtin_amdgcn_mfma_f32_16x16x32_bf16(al, b1h, acc1, 0, 0, 0);
        __syncthreads();
    }

    const int rq = (lane >> 4) * 4;
    #pragma unroll
    for (int f = 0; f < 2; ++f) {
        f32x4 acc = f ? acc1 : acc0;
        int n = n0 + wn + f * 16 + fr;
        float bb = bias[n];
        #pragma unroll
        for (int q = 0; q < 4; ++q) {
            int m = m0 + wm + rq + q;
            size_t off = (size_t)m * N + n;
            float v = acc[q] + bb;
            if (EPI == 0) {
                Cf[off] = v;
            } else if (EPI == 1) {
                short hh, ll; fsplit(v, hh, ll);
                Cbh[off] = hh; Cbl[off] = ll;
            } else if (EPI == 2) {
                v = fmaxf(v, 0.f) + addm[off];
                short hh, ll; fsplit(v, hh, ll);
                Cbh[off] = hh; Cbl[off] = ll;
            } else {
                Cf[off] = fmaxf(v, 0.f);
            }
        }
    }
}

// ---------------------------------------------------------------------------
// attention (one block per (batch, head)); accumulates mean_t(o) into obar
// ---------------------------------------------------------------------------
__global__ __launch_bounds__(256) void attn_kernel(const float* __restrict__ qkv,
                                                   float* __restrict__ obar, int b0) {
    __shared__ float Qs[FN][DH];
    __shared__ float Ks[FN][DH];
    __shared__ float Ss[FN][62];
    const int bl = blockIdx.x, h = blockIdx.y;
    const float* base = qkv + (size_t)bl * FN * 3 * HN + h * DH;
    for (int i = threadIdx.x; i < FN * DH; i += 256) {
        int t = i >> 8, d = i & 255;
        Qs[t][d] = base[(size_t)t * 3 * HN + d];
        Ks[t][d] = base[(size_t)t * 3 * HN + HN + d];
    }
    __syncthreads();
    for (int p = threadIdx.x; p < FN * FN; p += 256) {
        int qi = p / FN, kj = p - qi * FN;
        const float4* qp = (const float4*)&Qs[qi][0];
        const float4* kp = (const float4*)&Ks[kj][0];
        float s = 0.f;
        #pragma unroll
        for (int c = 0; c < DH / 4; ++c) {
            float4 a = qp[c], b = kp[c];
            s += a.x * b.x + a.y * b.y + a.z * b.z + a.w * b.w;
        }
        Ss[qi][kj] = s * 0.0625f;
    }
    __syncthreads();
    if (threadIdx.x < FN) {
        int qi = threadIdx.x;
        float mx = -1e30f;
        for (int j = 0; j < FN; ++j) mx = fmaxf(mx, Ss[qi][j]);
        float sm = 0.f;
        for (int j = 0; j < FN; ++j) { float e = expf(Ss[qi][j] - mx); Ss[qi][j] = e; sm += e; }
        float inv = 1.f / sm;
        for (int j = 0; j < FN; ++j) Ss[qi][j] *= inv;
    }
    __syncthreads();
    float* Vs = &Qs[0][0];
    for (int i = threadIdx.x; i < FN * DH; i += 256) {
        int t = i >> 8, d = i & 255;
        Vs[t * DH + d] = base[(size_t)t * 3 * HN + 2 * HN + d];
    }
    __syncthreads();
    int d = threadIdx.x;
    float accum = 0.f;
    for (int qi = 0; qi < FN; ++qi) {
        float o = 0.f;
        for (int j = 0; j < FN; ++j) o += Ss[qi][j] * Vs[j * DH + d];
        accum += o;
    }
    obar[(size_t)(b0 + bl) * HN + h * DH + d] = accum * (1.f / (float)FN);
}

// ---------------------------------------------------------------------------
// decoder prep / fused spl2+rot  (x kept as split pair [256][XWP])
// ---------------------------------------------------------------------------
__global__ __launch_bounds__(128) void prep_kernel(const float* __restrict__ poses,
                                                   float* __restrict__ sixd,
                                                   short* __restrict__ xdh,
                                                   short* __restrict__ xdl) {
    int b = blockIdx.x;
    const float* src = poses + ((size_t)b * TT + (TSEED - 1)) * DN;
    for (int d = threadIdx.x; d < DN; d += 128) {
        short hh, ll; fsplit(src[d], hh, ll);
        xdh[b * XWP + d] = hh; xdl[b * XWP + d] = ll;
    }
    for (int p = threadIdx.x; p < JN * 6; p += 128) {
        int j = p / 6, c = p - j * 6;
        int i = (c < 3) ? c : (c - 3);
        int col = (c < 3) ? 0 : 1;
        sixd[b * JN * 6 + p] = src[j * 9 + i * 3 + col];
    }
}

__global__ __launch_bounds__(128) void spl2rot_kernel(const float* __restrict__ z1,
                                                      const float* __restrict__ w2,
                                                      const float* __restrict__ b2,
                                                      float* __restrict__ sixd,
                                                      float* __restrict__ out, int t,
                                                      short* __restrict__ xdh,
                                                      short* __restrict__ xdl) {
    int b = blockIdx.x, p = threadIdx.x;
    if (p < JN * 6) {
        int j = p / 6, o = p - j * 6;
        const float* z = z1 + (size_t)b * (JN * 128) + j * 128;
        const float* wv = w2 + (j * 6 + o) * 128;
        float s = b2[j * 6 + o];
        #pragma unroll 4
        for (int k = 0; k < 128; ++k) s += z[k] * wv[k];
        float nv = sixd[b * JN * 6 + p] + s;
        sixd[b * JN * 6 + p] = nv;
        out[((size_t)b * PREDN + t) * (JN * 6) + p] = nv;
    }
    __syncthreads();
    if (p < JN) {
        int j = p;
        const float* v = sixd + b * JN * 6 + j * 6;
        float a1x = v[0], a1y = v[2], a1z = v[4];
        float a2x = v[1], a2y = v[3], a2z = v[5];
        float n1 = fmaxf(sqrtf(a1x * a1x + a1y * a1y + a1z * a1z), 1e-12f);
        float b1x = a1x / n1, b1y = a1y / n1, b1z = a1z / n1;
        float dt = b1x * a2x + b1y * a2y + b1z * a2z;
        float ox = a2x - dt * b1x, oy = a2y - dt * b1y, oz = a2z - dt * b1z;
        float n2 = fmaxf(sqrtf(ox * ox + oy * oy + oz * oz), 1e-12f);
        float b2x = ox / n2, b2y = oy / n2, b2z = oz / n2;
        float b3x = b1y * b2z - b1z * b2y;
        float b3y = b1z * b2x - b1x * b2z;
        float b3z = b1x * b2y - b1y * b2x;
        float r9[9] = {b1x, b2x, b3x, b1y, b2y, b3y, b1z, b2z, b3z};
        short* oh = xdh + (size_t)b * XWP + j * 9;
        short* ol = xdl + (size_t)b * XWP + j * 9;
        #pragma unroll
        for (int q = 0; q < 9; ++q) {
            short hh, ll; fsplit(r9[q], hh, ll);
            oh[q] = hh; ol[q] = ll;
        }
    }
}

// ---------------------------------------------------------------------------
extern "C" void kernel_launch(void* const* d_in, const int* in_sizes, int n_in,
                              void* d_out, int out_size, void* d_ws, size_t ws_size,
                              hipStream_t stream) {
    const float* poses  = (const float*)d_in[0];
    const float* freq_w = (const float*)d_in[1];
    const float* freq_b = (const float*)d_in[2];
    const float* ain_w  = (const float*)d_in[3];
    const float* ain_b  = (const float*)d_in[4];
    const float* aout_w = (const float*)d_in[5];
    const float* aout_b = (const float*)d_in[6];
    const float* wih0   = (const float*)d_in[7];
    const float* whh0   = (const float*)d_in[8];
    const float* bih0   = (const float*)d_in[9];
    const float* bhh0   = (const float*)d_in[10];
    const float* wih1   = (const float*)d_in[11];
    const float* whh1   = (const float*)d_in[12];
    const float* bih1   = (const float*)d_in[13];
    const float* bhh1   = (const float*)d_in[14];
    const float* pre_w  = (const float*)d_in[15];
    const float* pre_b  = (const float*)d_in[16];
    const float* spl_w1 = (const float*)d_in[17];
    const float* spl_b1 = (const float*)d_in[18];
    const float* spl_w2 = (const float*)d_in[19];
    const float* spl_b2 = (const float*)d_in[20];
    float* out = (float*)d_out;

    char* p = (char*)d_ws;
    auto alloc = [&](size_t bytes) { void* r = p; p += (bytes + 255) & ~(size_t)255; return r; };
    short* W0h    = (short*)alloc((size_t)4096 * KP0 * 2);
    short* W0l    = (short*)alloc((size_t)4096 * KP0 * 2);
    short* W1h    = (short*)alloc((size_t)4096 * KP1 * 2);
    short* W1l    = (short*)alloc((size_t)4096 * KP1 * 2);
    float* b0p    = (float*)alloc(4096 * 4);
    float* b1p    = (float*)alloc(4096 * 4);
    short* freqh  = (short*)alloc((size_t)1024 * KPF * 2);
    short* freql  = (short*)alloc((size_t)1024 * KPF * 2);
    short* ainh   = (short*)alloc((size_t)3072 * 1024 * 2);
    short* ainl   = (short*)alloc((size_t)3072 * 1024 * 2);
    short* aouth  = (short*)alloc((size_t)1024 * 1024 * 2);
    short* aoutl  = (short*)alloc((size_t)1024 * 1024 * 2);
    short* preh   = (short*)alloc((size_t)1024 * 1024 * 2);
    short* prel   = (short*)alloc((size_t)1024 * 1024 * 2);
    short* spl1h  = (short*)alloc((size_t)1920 * 1024 * 2);
    short* spl1l  = (short*)alloc((size_t)1920 * 1024 * 2);
    short* Xh     = (short*)alloc((size_t)TSEED * BB * XWP * 2);
    short* Xl     = (short*)alloc((size_t)TSEED * BB * XWP * 2);
    float* cosm   = (float*)alloc(FN * TSEED * 4);
    float* freqf  = (float*)alloc((size_t)BB * FN * DN * 4);
    short* feath  = (short*)alloc((size_t)RCH * HN * 2);
    short* featl  = (short*)alloc((size_t)RCH * HN * 2);
    float* qkvc   = (float*)alloc((size_t)RCH * 3 * HN * 4);
    float* obar   = (float*)alloc((size_t)BB * HN * 4);
    float* mctx   = (float*)alloc((size_t)BB * HN * 4);
    float* h0     = (float*)alloc((size_t)BB * HN * 4);
    float* h1     = (float*)alloc((size_t)BB * HN * 4);
    short* h0pA   = (short*)alloc((size_t)BB * HN * 2);
    short* h0lA   = (short*)alloc((size_t)BB * HN * 2);
    short* h0pB   = (short*)alloc((size_t)BB * HN * 2);
    short* h0lB   = (short*)alloc((size_t)BB * HN * 2);
    short* h1pA   = (short*)alloc((size_t)BB * HN * 2);
    short* h1lA   = (short*)alloc((size_t)BB * HN * 2);
    short* h1pB   = (short*)alloc((size_t)BB * HN * 2);
    short* h1lB   = (short*)alloc((size_t)BB * HN * 2);
    short* hidh   = (short*)alloc((size_t)BB * HN * 2);
    short* hidl   = (short*)alloc((size_t)BB * HN * 2);
    float* z1     = (float*)alloc((size_t)BB * JN * 128 * 4);
    float* sixd   = (float*)alloc((size_t)BB * JN * 6 * 4);
    short* xdh    = (short*)alloc((size_t)BB * XWP * 2);
    short* xdl    = (short*)alloc((size_t)BB * XWP * 2);

    // ---- prepack (every call; graph-safe) ----
    pack_gruw_i<<<4096, 256, 0, stream>>>(wih0, whh0, DN, XWP, KP0, W0h, W0l);
    pack_gruw_i<<<4096, 256, 0, stream>>>(wih1, whh1, HN, HN, KP1, W1h, W1l);
    pack_grub<<<16, 256, 0, stream>>>(bih0, bhh0, b0p);
    pack_grub<<<16, 256, 0, stream>>>(bih1, bhh1, b1p);
    castw<<<1024, 256, 0, stream>>>(freq_w, freqh, freql, DN, KPF);
    castw<<<3072, 256, 0, stream>>>(ain_w, ainh, ainl, HN, HN);
    castw<<<1024, 256, 0, stream>>>(aout_w, aouth, aoutl, HN, HN);
    castw<<<1024, 256, 0, stream>>>(pre_w, preh, prel, HN, HN);
    castw<<<1920, 256, 0, stream>>>(spl_w1, spl1h, spl1l, HN, HN);
    pack_x<<<TSEED, 256, 0, stream>>>(poses, Xh, Xl);

    // ---- encoder ----
    cos_kernel<<<FN, 128, 0, stream>>>(cosm);
    dft_kernel<<<BB, 256, 0, stream>>>(poses, cosm, freqf);
    for (int bc = 0; bc < BB / BCH; ++bc) {
        mgemm<1><<<dim3(RCH / 32, HN / 64), 256, 0, stream>>>(
            freqf + (size_t)bc * RCH * DN, DN, DN,
            nullptr, nullptr, 0, 0, nullptr, nullptr, 0, 0,
            freqh, freql, KPF, freq_b, nullptr, nullptr, feath, featl, HN);
        mgemm<0><<<dim3(RCH / 32, 3 * HN / 64), 256, 0, stream>>>(
            nullptr, 0, 0, feath, featl, HN, HN, nullptr, nullptr, 0, 0,
            ainh, ainl, HN, ain_b, nullptr, qkvc, nullptr, nullptr, 3 * HN);
        attn_kernel<<<dim3(BCH, 4), 256, 0, stream>>>(qkvc, obar, bc * BCH);
    }
    mgemm<0><<<dim3(BB / 32, HN / 64), 256, 0, stream>>>(
        obar, HN, HN, nullptr, nullptr, 0, 0, nullptr, nullptr, 0, 0,
        aouth, aoutl, HN, aout_b, nullptr, mctx, nullptr, nullptr, HN);

    // ---- GRU scan: 2 fused dispatches per step, ping-pong h pairs ----
    hipMemsetAsync(h0, 0, (size_t)BB * HN * 4, stream);
    hipMemsetAsync(h1, 0, (size_t)BB * HN * 4, stream);
    hipMemsetAsync(h0pA, 0, (size_t)BB * HN * 2, stream);
    hipMemsetAsync(h0lA, 0, (size_t)BB * HN * 2, stream);
    hipMemsetAsync(h1pA, 0, (size_t)BB * HN * 2, stream);
    hipMemsetAsync(h1lA, 0, (size_t)BB * HN * 2, stream);
    short *h0rh = h0pA, *h0rl = h0lA, *h0wh = h0pB, *h0wl = h0lB;
    short *h1rh = h1pA, *h1rl = h1lA, *h1wh = h1pB, *h1wl = h1lB;
    short* tmp;
    dim3 sgrid(4, 64);
    for (int t = 0; t < TSEED; ++t) {
        gru_scan<<<sgrid, 256, 0, stream>>>(
            Xh + (size_t)t * BB * XWP, Xl + (size_t)t * BB * XWP, XWP, XWP,
            h0rh, h0rl, HN, W0h, W0l, KP0, KP0 / 32, b0p, h0, h0wh, h0wl);
        tmp = h0rh; h0rh = h0wh; h0wh = tmp; tmp = h0rl; h0rl = h0wl; h0wl = tmp;
        gru_scan<<<sgrid, 256, 0, stream>>>(
            h0rh, h0rl, HN, HN, h1rh, h1rl, HN,
            W1h, W1l, KP1, KP1 / 32, b1p, h1, h1wh, h1wl);
        tmp = h1rh; h1rh = h1wh; h1wh = tmp; tmp = h1rl; h1rl = h1wl; h1wl = tmp;
    }

    // ---- decoder ----
    hipMemsetAsync(xdh, 0, (size_t)BB * XWP * 2, stream);
    hipMemsetAsync(xdl, 0, (size_t)BB * XWP * 2, stream);
    prep_kernel<<<BB, 128, 0, stream>>>(poses, sixd, xdh, xdl);
    for (int t = 0; t < PREDN; ++t) {
        gru_scan<<<sgrid, 256, 0, stream>>>(
            xdh, xdl, XWP, XWP, h0rh, h0rl, HN,
            W0h, W0l, KP0, KP0 / 32, b0p, h0, h0wh, h0wl);
        tmp = h0rh; h0rh = h0wh; h0wh = tmp; tmp = h0rl; h0rl = h0wl; h0wl = tmp;
        gru_scan<<<sgrid, 256, 0, stream>>>(
            h0rh, h0rl, HN, HN, h1rh, h1rl, HN,
            W1h, W1l, KP1, KP1 / 32, b1p, h1, h1wh, h1wl);
        tmp = h1rh; h1rh = h1wh; h1wh = tmp; tmp = h1rl; h1rl = h1wl; h1wl = tmp;
        mgemm<2><<<dim3(BB / 32, HN / 64), 256, 0, stream>>>(
            nullptr, 0, 0, h1rh, h1rl, HN, HN, nullptr, nullptr, 0, 0,
            preh, prel, HN, pre_b, mctx, nullptr, hidh, hidl, HN);
        mgemm<3><<<dim3(BB / 32, 1920 / 64), 256, 0, stream>>>(
            nullptr, 0, 0, hidh, hidl, HN, HN, nullptr, nullptr, 0, 0,
            spl1h, spl1l, HN, spl_b1, nullptr, z1, nullptr, nullptr, 1920);
        spl2rot_kernel<<<BB, 128, 0, stream>>>(z1, spl_w2, spl_b2, sixd, out, t, xdh, xdl);
    }
}

// Round 7
// 10860.211 us; speedup vs baseline: 1.9876x; 1.2661x over previous
//
#include <hip/hip_runtime.h>

#define BB     256
#define TSEED  120
#define PREDN  24
#define JN     15
#define HN     1024
#define DN     135
#define FN     61
#define TT     144
#define DH     256
#define BCH    64
#define RCH    (BCH*FN)   // 3904 rows per encoder chunk
#define KPF    160        // 135 padded for freq weights
#define XWP    160        // padded x width for GRU layer0
#define KP0    (XWP+HN)   // 1184
#define KP1    (2*HN)     // 2048

typedef __attribute__((ext_vector_type(8))) short short8v;
typedef __attribute__((ext_vector_type(4))) float f32x4;

__device__ __forceinline__ short f2b(float f) {
    union { float f; unsigned u; } v; v.f = f;
    unsigned r = (v.u + 0x7FFFu + ((v.u >> 16) & 1u)) >> 16;
    return (short)r;
}
__device__ __forceinline__ float b2f(short h) {
    union { unsigned u; float f; } x; x.u = ((unsigned)(unsigned short)h) << 16; return x.f;
}
__device__ __forceinline__ void fsplit(float v, short& h, short& l) {
    h = f2b(v); l = f2b(v - b2f(h));
}

// ---------------------------------------------------------------------------
// prepack kernels (unchanged from round 6)
// ---------------------------------------------------------------------------
__global__ __launch_bounds__(256) void pack_gruw_i(const float* __restrict__ wih,
                                                   const float* __restrict__ whh,
                                                   int KX, int XW, int KP,
                                                   short* __restrict__ Wh,
                                                   short* __restrict__ Wl) {
    int np = blockIdx.x;
    int jb = np >> 6, g = (np >> 4) & 3, jj = np & 15;
    int j = jb * 16 + jj;
    for (int k = threadIdx.x; k < KP; k += 256) {
        float v = 0.f;
        if (k < KX) {
            if (g < 3) v = wih[(size_t)(g * HN + j) * KX + k];
        } else if (k >= XW) {
            int kk = k - XW;
            if (g == 0)      v = whh[(size_t)j * HN + kk];
            else if (g == 1) v = whh[(size_t)(HN + j) * HN + kk];
            else if (g == 3) v = whh[(size_t)(2 * HN + j) * HN + kk];
        }
        short hh, ll; fsplit(v, hh, ll);
        Wh[(size_t)np * KP + k] = hh;
        Wl[(size_t)np * KP + k] = ll;
    }
}

__global__ __launch_bounds__(256) void pack_grub(const float* __restrict__ bih,
                                                 const float* __restrict__ bhh,
                                                 float* __restrict__ bp) {
    int n = blockIdx.x * 256 + threadIdx.x;
    if (n < 4 * HN) {
        int g = n >> 10, j = n & 1023;
        float v;
        if (g == 0)      v = bih[j] + bhh[j];
        else if (g == 1) v = bih[HN + j] + bhh[HN + j];
        else if (g == 2) v = bih[2 * HN + j];
        else             v = bhh[2 * HN + j];
        bp[n] = v;
    }
}

__global__ __launch_bounds__(256) void castw(const float* __restrict__ w,
                                             short* __restrict__ oh,
                                             short* __restrict__ ol, int K, int KP) {
    int n = blockIdx.x;
    for (int k = threadIdx.x; k < KP; k += 256) {
        float v = (k < K) ? w[(size_t)n * K + k] : 0.f;
        short hh, ll; fsplit(v, hh, ll);
        oh[(size_t)n * KP + k] = hh;
        ol[(size_t)n * KP + k] = ll;
    }
}

__global__ __launch_bounds__(256) void pack_x(const float* __restrict__ poses,
                                              short* __restrict__ Xh,
                                              short* __restrict__ Xl) {
    int t = blockIdx.x;
    short* oh = Xh + (size_t)t * BB * XWP;
    short* ol = Xl + (size_t)t * BB * XWP;
    for (int i = threadIdx.x; i < BB * XWP; i += 256) {
        int b = i / XWP, k = i - b * XWP;
        float v = (k < DN) ? poses[((size_t)b * TT + t) * DN + k] : 0.f;
        short hh, ll; fsplit(v, hh, ll);
        oh[i] = hh; ol[i] = ll;
    }
}

// ---------------------------------------------------------------------------
// cos table + DFT (real part of rfft)
// ---------------------------------------------------------------------------
__global__ __launch_bounds__(128) void cos_kernel(float* __restrict__ cosm) {
    int f = blockIdx.x, t = threadIdx.x;
    if (t < TSEED) {
        int ft = (f * t) % TSEED;
        cosm[f * TSEED + t] = cosf((float)ft * (6.283185307179586f / (float)TSEED));
    }
}

__global__ __launch_bounds__(256) void dft_kernel(const float* __restrict__ poses,
                                                  const float* __restrict__ cosm,
                                                  float* __restrict__ freq) {
    __shared__ float cs[FN * TSEED];
    for (int i = threadIdx.x; i < FN * TSEED; i += 256) cs[i] = cosm[i];
    __syncthreads();
    const float* xp = poses + (size_t)blockIdx.x * TT * DN;
    float* fp = freq + (size_t)blockIdx.x * FN * DN;
    for (int o = threadIdx.x; o < FN * DN; o += 256) {
        int f = o / DN, d = o - f * DN;
        const float* cf = &cs[f * TSEED];
        float s = 0.f;
        #pragma unroll 4
        for (int t = 0; t < TSEED; ++t) s += xp[t * DN + d] * cf[t];
        fp[o] = s;
    }
}

// ---------------------------------------------------------------------------
// Paired GRU scan step.  Grid (4 m-blocks, 64 jb, nroles<=2); role from
// blockIdx.z.  Pairing rule: dispatch D_t = { L0(t+1), L1(t) } — both
// depend only on state finished before D_t.  2 blocks/CU -> 8 waves/CU.
// Block 64x64, 4 waves 32x32, LDS [row][40] (<=2-way conflicts).
// ---------------------------------------------------------------------------
struct GruArgs {
    const short *A1h, *A1l; int w1, s1;
    const short *A2h, *A2l; int s2;
    const short *Wh, *Wl; int KP, NCH;
    const float* bp;
    float* hf; short *hoh, *hol;
};

__global__ __launch_bounds__(256, 2) void gru_pair(GruArgs g0, GruArgs g1) {
    const GruArgs g = (blockIdx.z == 0) ? g0 : g1;
    __shared__ __align__(16) char smem[20480];
    short* Ash = (short*)smem;          // [64][40]
    short* Asl = Ash + 64 * 40;
    short* Bsh = Asl + 64 * 40;
    short* Bsl = Bsh + 64 * 40;
    float* gbuf = (float*)smem;         // [64][65] floats

    const int tid = threadIdx.x;
    const int m0 = blockIdx.x * 64;
    const int jb = blockIdx.y;
    const int n0 = jb * 64;
    const int lane = tid & 63, wv = tid >> 6;
    const int mslot = wv & 1, nslot = wv >> 1;
    const int fr = lane & 15, kg = lane >> 4;
    const int rq = kg * 4;
    const int ldr = tid >> 2, ldk = tid & 3;
    f32x4 acc[2][2];
    acc[0][0] = (f32x4){0.f,0.f,0.f,0.f}; acc[0][1] = (f32x4){0.f,0.f,0.f,0.f};
    acc[1][0] = (f32x4){0.f,0.f,0.f,0.f}; acc[1][1] = (f32x4){0.f,0.f,0.f,0.f};

    short8v rAh, rAl, rBh, rBl;
    auto loadA = [&](int c) {
        int kglob = c * 32;
        const short *ph, *pl; int st, ko;
        if (kglob < g.w1) { ph = g.A1h; pl = g.A1l; st = g.s1; ko = kglob; }
        else              { ph = g.A2h; pl = g.A2l; st = g.s2; ko = kglob - g.w1; }
        size_t o = (size_t)(m0 + ldr) * st + ko + ldk * 8;
        rAh = *(const short8v*)(ph + o); rAl = *(const short8v*)(pl + o);
    };
    auto loadB = [&](int c) {
        size_t o = (size_t)(n0 + ldr) * g.KP + c * 32 + ldk * 8;
        rBh = *(const short8v*)(g.Wh + o); rBl = *(const short8v*)(g.Wl + o);
    };

    loadA(0); loadB(0);
    for (int c = 0; c < g.NCH; ++c) {
        __syncthreads();
        *(short8v*)&Ash[ldr * 40 + ldk * 8] = rAh;
        *(short8v*)&Asl[ldr * 40 + ldk * 8] = rAl;
        *(short8v*)&Bsh[ldr * 40 + ldk * 8] = rBh;
        *(short8v*)&Bsl[ldr * 40 + ldk * 8] = rBl;
        if (c + 1 < g.NCH) { loadA(c + 1); loadB(c + 1); }
        __syncthreads();
        short8v ah0 = *(const short8v*)&Ash[(mslot * 32 + fr) * 40 + kg * 8];
        short8v ah1 = *(const short8v*)&Ash[(mslot * 32 + 16 + fr) * 40 + kg * 8];
        short8v al0 = *(const short8v*)&Asl[(mslot * 32 + fr) * 40 + kg * 8];
        short8v al1 = *(const short8v*)&Asl[(mslot * 32 + 16 + fr) * 40 + kg * 8];
        short8v bh0 = *(const short8v*)&Bsh[(nslot * 32 + fr) * 40 + kg * 8];
        short8v bh1 = *(const short8v*)&Bsh[(nslot * 32 + 16 + fr) * 40 + kg * 8];
        short8v bl0 = *(const short8v*)&Bsl[(nslot * 32 + fr) * 40 + kg * 8];
        short8v bl1 = *(const short8v*)&Bsl[(nslot * 32 + 16 + fr) * 40 + kg * 8];
        acc[0][0] = __builtin_amdgcn_mfma_f32_16x16x32_bf16(ah0, bh0, acc[0][0], 0, 0, 0);
        acc[0][0] = __builtin_amdgcn_mfma_f32_16x16x32_bf16(ah0, bl0, acc[0][0], 0, 0, 0);
        acc[0][0] = __builtin_amdgcn_mfma_f32_16x16x32_bf16(al0, bh0, acc[0][0], 0, 0, 0);
        acc[0][1] = __builtin_amdgcn_mfma_f32_16x16x32_bf16(ah0, bh1, acc[0][1], 0, 0, 0);
        acc[0][1] = __builtin_amdgcn_mfma_f32_16x16x32_bf16(ah0, bl1, acc[0][1], 0, 0, 0);
        acc[0][1] = __builtin_amdgcn_mfma_f32_16x16x32_bf16(al0, bh1, acc[0][1], 0, 0, 0);
        acc[1][0] = __builtin_amdgcn_mfma_f32_16x16x32_bf16(ah1, bh0, acc[1][0], 0, 0, 0);
        acc[1][0] = __builtin_amdgcn_mfma_f32_16x16x32_bf16(ah1, bl0, acc[1][0], 0, 0, 0);
        acc[1][0] = __builtin_amdgcn_mfma_f32_16x16x32_bf16(al1, bh0, acc[1][0], 0, 0, 0);
        acc[1][1] = __builtin_amdgcn_mfma_f32_16x16x32_bf16(ah1, bh1, acc[1][1], 0, 0, 0);
        acc[1][1] = __builtin_amdgcn_mfma_f32_16x16x32_bf16(ah1, bl1, acc[1][1], 0, 0, 0);
        acc[1][1] = __builtin_amdgcn_mfma_f32_16x16x32_bf16(al1, bh1, acc[1][1], 0, 0, 0);
        __syncthreads();
    }

    __syncthreads();
    #pragma unroll
    for (int mi = 0; mi < 2; ++mi) {
        #pragma unroll
        for (int nf = 0; nf < 2; ++nf) {
            int ml = mslot * 32 + mi * 16 + rq;
            int cn = nslot * 32 + nf * 16 + fr;
            #pragma unroll
            for (int q = 0; q < 4; ++q)
                gbuf[(ml + q) * 65 + cn] = acc[mi][nf][q];
        }
    }
    __syncthreads();

    #pragma unroll
    for (int rep = 0; rep < 4; ++rep) {
        int idx = tid + rep * 256;
        int ml = idx >> 4, jj = idx & 15;
        int j = jb * 16 + jj;
        float r  = gbuf[ml * 65 + jj]       + g.bp[j];
        float z  = gbuf[ml * 65 + 16 + jj]  + g.bp[HN + j];
        float gi = gbuf[ml * 65 + 32 + jj]  + g.bp[2 * HN + j];
        float gh = gbuf[ml * 65 + 48 + jj]  + g.bp[3 * HN + j];
        r = 1.f / (1.f + expf(-r));
        z = 1.f / (1.f + expf(-z));
        float n = tanhf(gi + r * gh);
        size_t off = (size_t)(m0 + ml) * HN + j;
        float hp = g.hf[off];
        float hv = (1.f - z) * n + z * hp;
        g.hf[off] = hv;
        short hh, ll; fsplit(hv, hh, ll);
        g.hoh[off] = hh; g.hol[off] = ll;
    }
}

// ---------------------------------------------------------------------------
// Split-bf16 MFMA GEMM (general, 32x64 tile) — encoder + decoder pre.
// EPI: 0 bias->f32 | 1 bias->pair | 2 relu(v+bias)+addm->pair
// ---------------------------------------------------------------------------
template<int EPI>
__global__ __launch_bounds__(256) void mgemm(
        const float* __restrict__ A0, int a0w, int a0s,
        const short* __restrict__ A1h, const short* __restrict__ A1l, int a1w, int a1s,
        const short* __restrict__ Bh, const short* __restrict__ Bl, int KP,
        const float* __restrict__ bias, const float* __restrict__ addm,
        float* __restrict__ Cf, short* __restrict__ Cbh, short* __restrict__ Cbl,
        int N) {
    __shared__ short Ash[32][40];
    __shared__ short Asl[32][40];
    __shared__ short Bsh[64][40];
    __shared__ short Bsl[64][40];
    const int tid = threadIdx.x;
    const int m0 = blockIdx.x * 32, n0 = blockIdx.y * 64;
    const int ra = tid >> 3, ka = (tid & 7) * 4;
    const int rb = tid >> 2, kb = (tid & 3) * 8;
    const int lane = tid & 63, wv = tid >> 6;
    const int wm = (wv & 1) * 16, wn = (wv >> 1) * 32;
    const int fr = lane & 15, fo = (lane >> 4) * 8;
    f32x4 acc0 = {0.f, 0.f, 0.f, 0.f}, acc1 = {0.f, 0.f, 0.f, 0.f};

    auto ldA = [&](int k, short& hh, short& ll) {
        if (k < a0w) {
            fsplit(A0[(size_t)(m0 + ra) * a0s + k], hh, ll);
        } else if (k < a0w + a1w) {
            size_t o = (size_t)(m0 + ra) * a1s + (k - a0w);
            hh = A1h[o]; ll = A1l[o];
        } else { hh = 0; ll = 0; }
    };

    short avh[4], avl[4];
    short8v bvh, bvl;
    #pragma unroll
    for (int j = 0; j < 4; ++j) ldA(ka + j, avh[j], avl[j]);
    bvh = *(const short8v*)(Bh + (size_t)(n0 + rb) * KP + kb);
    bvl = *(const short8v*)(Bl + (size_t)(n0 + rb) * KP + kb);

    for (int k0 = 0; k0 < KP; k0 += 32) {
        #pragma unroll
        for (int j = 0; j < 4; ++j) { Ash[ra][ka + j] = avh[j]; Asl[ra][ka + j] = avl[j]; }
        *(short8v*)&Bsh[rb][kb] = bvh;
        *(short8v*)&Bsl[rb][kb] = bvl;
        int kn = k0 + 32;
        if (kn < KP) {
            #pragma unroll
            for (int j = 0; j < 4; ++j) ldA(kn + ka + j, avh[j], avl[j]);
            bvh = *(const short8v*)(Bh + (size_t)(n0 + rb) * KP + kn + kb);
            bvl = *(const short8v*)(Bl + (size_t)(n0 + rb) * KP + kn + kb);
        }
        __syncthreads();
        short8v ah  = *(const short8v*)&Ash[wm + fr][fo];
        short8v al  = *(const short8v*)&Asl[wm + fr][fo];
        short8v b0h = *(const short8v*)&Bsh[wn + fr][fo];
        short8v b0l = *(const short8v*)&Bsl[wn + fr][fo];
        short8v b1h = *(const short8v*)&Bsh[wn + 16 + fr][fo];
        short8v b1l = *(const short8v*)&Bsl[wn + 16 + fr][fo];
        acc0 = __builtin_amdgcn_mfma_f32_16x16x32_bf16(ah, b0h, acc0, 0, 0, 0);
        acc0 = __builtin_amdgcn_mfma_f32_16x16x32_bf16(ah, b0l, acc0, 0, 0, 0);
        acc0 = __builtin_amdgcn_mfma_f32_16x16x32_bf16(al, b0h, acc0, 0, 0, 0);
        acc1 = __builtin_amdgcn_mfma_f32_16x16x32_bf16(ah, b1h, acc1, 0, 0, 0);
        acc1 = __builtin_amdgcn_mfma_f32_16x16x32_bf16(ah, b1l, acc1, 0, 0, 0);
        acc1 = __builtin_amdgcn_mfma_f32_16x16x32_bf16(al, b1h, acc1, 0, 0, 0);
        __syncthreads();
    }

    const int rq = (lane >> 4) * 4;
    #pragma unroll
    for (int f = 0; f < 2; ++f) {
        f32x4 acc = f ? acc1 : acc0;
        int n = n0 + wn + f * 16 + fr;
        float bb = bias[n];
        #pragma unroll
        for (int q = 0; q < 4; ++q) {
            int m = m0 + wm + rq + q;
            size_t off = (size_t)m * N + n;
            float v = acc[q] + bb;
            if (EPI == 0) {
                Cf[off] = v;
            } else if (EPI == 1) {
                short hh, ll; fsplit(v, hh, ll);
                Cbh[off] = hh; Cbl[off] = ll;
            } else {
                v = fmaxf(v, 0.f) + addm[off];
                short hh, ll; fsplit(v, hh, ll);
                Cbh[off] = hh; Cbl[off] = ll;
            }
        }
    }
}

// ---------------------------------------------------------------------------
// attention (one block per (chunk-batch, head)); writes mean_t(o) into obar
// ---------------------------------------------------------------------------
__global__ __launch_bounds__(256) void attn_kernel(const float* __restrict__ qkv,
                                                   float* __restrict__ obar, int b0) {
    __shared__ float Qs[FN][DH];
    __shared__ float Ks[FN][DH];
    __shared__ float Ss[FN][62];
    const int bl = blockIdx.x, h = blockIdx.y;
    const float* base = qkv + (size_t)bl * FN * 3 * HN + h * DH;
    for (int i = threadIdx.x; i < FN * DH; i += 256) {
        int t = i >> 8, d = i & 255;
        Qs[t][d] = base[(size_t)t * 3 * HN + d];
        Ks[t][d] = base[(size_t)t * 3 * HN + HN + d];
    }
    __syncthreads();
    for (int p = threadIdx.x; p < FN * FN; p += 256) {
        int qi = p / FN, kj = p - qi * FN;
        const float4* qp = (const float4*)&Qs[qi][0];
        const float4* kp = (const float4*)&Ks[kj][0];
        float s = 0.f;
        #pragma unroll
        for (int c = 0; c < DH / 4; ++c) {
            float4 a = qp[c], b = kp[c];
            s += a.x * b.x + a.y * b.y + a.z * b.z + a.w * b.w;
        }
        Ss[qi][kj] = s * 0.0625f;
    }
    __syncthreads();
    if (threadIdx.x < FN) {
        int qi = threadIdx.x;
        float mx = -1e30f;
        for (int j = 0; j < FN; ++j) mx = fmaxf(mx, Ss[qi][j]);
        float sm = 0.f;
        for (int j = 0; j < FN; ++j) { float e = expf(Ss[qi][j] - mx); Ss[qi][j] = e; sm += e; }
        float inv = 1.f / sm;
        for (int j = 0; j < FN; ++j) Ss[qi][j] *= inv;
    }
    __syncthreads();
    float* Vs = &Qs[0][0];
    for (int i = threadIdx.x; i < FN * DH; i += 256) {
        int t = i >> 8, d = i & 255;
        Vs[t * DH + d] = base[(size_t)t * 3 * HN + 2 * HN + d];
    }
    __syncthreads();
    int d = threadIdx.x;
    float accum = 0.f;
    for (int qi = 0; qi < FN; ++qi) {
        float o = 0.f;
        for (int j = 0; j < FN; ++j) o += Ss[qi][j] * Vs[j * DH + d];
        accum += o;
    }
    obar[(size_t)(b0 + bl) * HN + h * DH + d] = accum * (1.f / (float)FN);
}

// ---------------------------------------------------------------------------
// decoder prep
// ---------------------------------------------------------------------------
__global__ __launch_bounds__(128) void prep_kernel(const float* __restrict__ poses,
                                                   float* __restrict__ sixd,
                                                   short* __restrict__ xdh,
                                                   short* __restrict__ xdl) {
    int b = blockIdx.x;
    const float* src = poses + ((size_t)b * TT + (TSEED - 1)) * DN;
    for (int d = threadIdx.x; d < DN; d += 128) {
        short hh, ll; fsplit(src[d], hh, ll);
        xdh[b * XWP + d] = hh; xdl[b * XWP + d] = ll;
    }
    for (int p = threadIdx.x; p < JN * 6; p += 128) {
        int j = p / 6, c = p - j * 6;
        int i = (c < 3) ? c : (c - 3);
        int col = (c < 3) ? 0 : 1;
        sixd[b * JN * 6 + p] = src[j * 9 + i * 3 + col];
    }
}

// ---------------------------------------------------------------------------
// Fused spl1 + spl2 + rot6d.  Grid (8 m-blocks x JN joints), 256 thr (4 waves).
// Block: z1[32 rows][128 cols of joint j] = relu(hidden @ spl1_j^T + b1) kept
// in LDS; then delta (6-wide dots), sixd+=, out write, rot6d -> xd pair.
// ---------------------------------------------------------------------------
__global__ __launch_bounds__(256) void fsplrot(
        const short* __restrict__ hidh, const short* __restrict__ hidl,
        const short* __restrict__ s1h, const short* __restrict__ s1l,
        const float* __restrict__ b1, const float* __restrict__ w2,
        const float* __restrict__ b2,
        float* __restrict__ sixd, float* __restrict__ out, int td,
        short* __restrict__ xdh, short* __restrict__ xdl) {
    __shared__ __align__(16) char smem[30720];
    short* Ash = (short*)smem;                 // [32][40]
    short* Asl = Ash + 32 * 40;
    short* Bsh = Asl + 32 * 40;                // [128][40]
    short* Bsl = Bsh + 128 * 40;               // tiles end at byte 25600
    float* zbuf = (float*)smem;                // [32][132] = 16896 B (overlay)
    float* w2s  = (float*)(smem + 26112);      // 768 floats
    float* dv   = w2s + 768;                   // 192 floats
    const int tid = threadIdx.x;
    const int m0 = blockIdx.x * 32;
    const int j  = blockIdx.y;
    const int lane = tid & 63, wv = tid >> 6;
    const int fr = lane & 15, kg = lane >> 4;

    for (int i = tid; i < 768; i += 256) w2s[i] = w2[(size_t)j * 768 + i];

    f32x4 acc[2][2];
    acc[0][0] = (f32x4){0.f,0.f,0.f,0.f}; acc[0][1] = (f32x4){0.f,0.f,0.f,0.f};
    acc[1][0] = (f32x4){0.f,0.f,0.f,0.f}; acc[1][1] = (f32x4){0.f,0.f,0.f,0.f};

    short8v a_pre, b_pre[4];
    auto loadA = [&](int c) {
        int slot = tid & 127; int row = slot >> 2, k2 = slot & 3;
        size_t o = (size_t)(m0 + row) * HN + c * 32 + k2 * 8;
        a_pre = (tid < 128) ? *(const short8v*)(hidh + o) : *(const short8v*)(hidl + o);
    };
    auto loadB = [&](int c) {
        #pragma unroll
        for (int r = 0; r < 4; ++r) {
            int slot = tid + r * 256;
            int s2 = slot & 511; int row = s2 >> 2, k2 = s2 & 3;
            size_t o = (size_t)(j * 128 + row) * HN + c * 32 + k2 * 8;
            b_pre[r] = (slot < 512) ? *(const short8v*)(s1h + o) : *(const short8v*)(s1l + o);
        }
    };

    loadA(0); loadB(0);
    for (int c = 0; c < HN / 32; ++c) {
        __syncthreads();
        {
            int slot = tid & 127; int row = slot >> 2, k2 = slot & 3;
            short* dst = (tid < 128) ? Ash : Asl;
            *(short8v*)&dst[row * 40 + k2 * 8] = a_pre;
        }
        #pragma unroll
        for (int r = 0; r < 4; ++r) {
            int slot = tid + r * 256;
            int s2 = slot & 511; int row = s2 >> 2, k2 = s2 & 3;
            short* dst = (slot < 512) ? Bsh : Bsl;
            *(short8v*)&dst[row * 40 + k2 * 8] = b_pre[r];
        }
        if (c + 1 < HN / 32) { loadA(c + 1); loadB(c + 1); }
        __syncthreads();
        short8v ah0 = *(const short8v*)&Ash[fr * 40 + kg * 8];
        short8v ah1 = *(const short8v*)&Ash[(16 + fr) * 40 + kg * 8];
        short8v al0 = *(const short8v*)&Asl[fr * 40 + kg * 8];
        short8v al1 = *(const short8v*)&Asl[(16 + fr) * 40 + kg * 8];
        #pragma unroll
        for (int nf = 0; nf < 2; ++nf) {
            short8v bh = *(const short8v*)&Bsh[(wv * 32 + nf * 16 + fr) * 40 + kg * 8];
            short8v bl = *(const short8v*)&Bsl[(wv * 32 + nf * 16 + fr) * 40 + kg * 8];
            acc[0][nf] = __builtin_amdgcn_mfma_f32_16x16x32_bf16(ah0, bh, acc[0][nf], 0, 0, 0);
            acc[0][nf] = __builtin_amdgcn_mfma_f32_16x16x32_bf16(ah0, bl, acc[0][nf], 0, 0, 0);
            acc[0][nf] = __builtin_amdgcn_mfma_f32_16x16x32_bf16(al0, bh, acc[0][nf], 0, 0, 0);
            acc[1][nf] = __builtin_amdgcn_mfma_f32_16x16x32_bf16(ah1, bh, acc[1][nf], 0, 0, 0);
            acc[1][nf] = __builtin_amdgcn_mfma_f32_16x16x32_bf16(ah1, bl, acc[1][nf], 0, 0, 0);
            acc[1][nf] = __builtin_amdgcn_mfma_f32_16x16x32_bf16(al1, bh, acc[1][nf], 0, 0, 0);
        }
        __syncthreads();
    }

    __syncthreads();   // tiles dead; overlay zbuf
    #pragma unroll
    for (int mi = 0; mi < 2; ++mi) {
        #pragma unroll
        for (int nf = 0; nf < 2; ++nf) {
            #pragma unroll
            for (int q = 0; q < 4; ++q) {
                int row = mi * 16 + kg * 4 + q;
                int col = wv * 32 + nf * 16 + fr;
                float v = acc[mi][nf][q] + b1[j * 128 + col];
                zbuf[row * 132 + col] = fmaxf(v, 0.f);
            }
        }
    }
    __syncthreads();

    if (tid < 192) {
        int row = tid / 6, o = tid - row * 6;
        float s = b2[j * 6 + o];
        const float* z = &zbuf[row * 132];
        const float* w = &w2s[o * 128];
        #pragma unroll 4
        for (int k = 0; k < 128; ++k) s += z[k] * w[k];
        size_t soff = (size_t)(m0 + row) * (JN * 6) + j * 6 + o;
        float nv = sixd[soff] + s;
        sixd[soff] = nv;
        out[((size_t)(m0 + row) * PREDN + td) * (JN * 6) + j * 6 + o] = nv;
        dv[row * 6 + o] = nv;
    }
    __syncthreads();

    if (tid < 32) {
        const float* v = &dv[tid * 6];
        float a1x = v[0], a1y = v[2], a1z = v[4];
        float a2x = v[1], a2y = v[3], a2z = v[5];
        float n1 = fmaxf(sqrtf(a1x * a1x + a1y * a1y + a1z * a1z), 1e-12f);
        float b1x = a1x / n1, b1y = a1y / n1, b1z = a1z / n1;
        float dt = b1x * a2x + b1y * a2y + b1z * a2z;
        float ox = a2x - dt * b1x, oy = a2y - dt * b1y, oz = a2z - dt * b1z;
        float n2 = fmaxf(sqrtf(ox * ox + oy * oy + oz * oz), 1e-12f);
        float b2x = ox / n2, b2y = oy / n2, b2z = oz / n2;
        float b3x = b1y * b2z - b1z * b2y;
        float b3y = b1z * b2x - b1x * b2z;
        float b3z = b1x * b2y - b1y * b2x;
        float r9[9] = {b1x, b2x, b3x, b1y, b2y, b3y, b1z, b2z, b3z};
        short* oh = xdh + (size_t)(m0 + tid) * XWP + j * 9;
        short* ol = xdl + (size_t)(m0 + tid) * XWP + j * 9;
        #pragma unroll
        for (int q = 0; q < 9; ++q) {
            short hh, ll; fsplit(r9[q], hh, ll);
            oh[q] = hh; ol[q] = ll;
        }
    }
}

// ---------------------------------------------------------------------------
extern "C" void kernel_launch(void* const* d_in, const int* in_sizes, int n_in,
                              void* d_out, int out_size, void* d_ws, size_t ws_size,
                              hipStream_t stream) {
    const float* poses  = (const float*)d_in[0];
    const float* freq_w = (const float*)d_in[1];
    const float* freq_b = (const float*)d_in[2];
    const float* ain_w  = (const float*)d_in[3];
    const float* ain_b  = (const float*)d_in[4];
    const float* aout_w = (const float*)d_in[5];
    const float* aout_b = (const float*)d_in[6];
    const float* wih0   = (const float*)d_in[7];
    const float* whh0   = (const float*)d_in[8];
    const float* bih0   = (const float*)d_in[9];
    const float* bhh0   = (const float*)d_in[10];
    const float* wih1   = (const float*)d_in[11];
    const float* whh1   = (const float*)d_in[12];
    const float* bih1   = (const float*)d_in[13];
    const float* bhh1   = (const float*)d_in[14];
    const float* pre_w  = (const float*)d_in[15];
    const float* pre_b  = (const float*)d_in[16];
    const float* spl_w1 = (const float*)d_in[17];
    const float* spl_b1 = (const float*)d_in[18];
    const float* spl_w2 = (const float*)d_in[19];
    const float* spl_b2 = (const float*)d_in[20];
    float* out = (float*)d_out;

    char* p = (char*)d_ws;
    auto alloc = [&](size_t bytes) { void* r = p; p += (bytes + 255) & ~(size_t)255; return r; };
    short* W0h    = (short*)alloc((size_t)4096 * KP0 * 2);
    short* W0l    = (short*)alloc((size_t)4096 * KP0 * 2);
    short* W1h    = (short*)alloc((size_t)4096 * KP1 * 2);
    short* W1l    = (short*)alloc((size_t)4096 * KP1 * 2);
    float* b0p    = (float*)alloc(4096 * 4);
    float* b1p    = (float*)alloc(4096 * 4);
    short* freqh  = (short*)alloc((size_t)1024 * KPF * 2);
    short* freql  = (short*)alloc((size_t)1024 * KPF * 2);
    short* ainh   = (short*)alloc((size_t)3072 * 1024 * 2);
    short* ainl   = (short*)alloc((size_t)3072 * 1024 * 2);
    short* aouth  = (short*)alloc((size_t)1024 * 1024 * 2);
    short* aoutl  = (short*)alloc((size_t)1024 * 1024 * 2);
    short* preh   = (short*)alloc((size_t)1024 * 1024 * 2);
    short* prel   = (short*)alloc((size_t)1024 * 1024 * 2);
    short* spl1h  = (short*)alloc((size_t)1920 * 1024 * 2);
    short* spl1l  = (short*)alloc((size_t)1920 * 1024 * 2);
    short* Xh     = (short*)alloc((size_t)TSEED * BB * XWP * 2);
    short* Xl     = (short*)alloc((size_t)TSEED * BB * XWP * 2);
    float* cosm   = (float*)alloc(FN * TSEED * 4);
    float* freqf  = (float*)alloc((size_t)BB * FN * DN * 4);
    short* feath  = (short*)alloc((size_t)RCH * HN * 2);
    short* featl  = (short*)alloc((size_t)RCH * HN * 2);
    float* qkvc   = (float*)alloc((size_t)RCH * 3 * HN * 4);
    float* obar   = (float*)alloc((size_t)BB * HN * 4);
    float* mctx   = (float*)alloc((size_t)BB * HN * 4);
    short* hidh   = (short*)alloc((size_t)BB * HN * 2);
    short* hidl   = (short*)alloc((size_t)BB * HN * 2);
    float* sixd   = (float*)alloc((size_t)BB * JN * 6 * 4);
    // ---- contiguous zero-init region ----
    char* zbase = p;
    float* h0f  = (float*)alloc((size_t)BB * HN * 4);
    float* h1f  = (float*)alloc((size_t)BB * HN * 4);
    short* h0p_[2]; short* h0l_[2]; short* h1p_[2]; short* h1l_[2];
    h0p_[0] = (short*)alloc((size_t)BB * HN * 2);
    h0l_[0] = (short*)alloc((size_t)BB * HN * 2);
    h0p_[1] = (short*)alloc((size_t)BB * HN * 2);
    h0l_[1] = (short*)alloc((size_t)BB * HN * 2);
    h1p_[0] = (short*)alloc((size_t)BB * HN * 2);
    h1l_[0] = (short*)alloc((size_t)BB * HN * 2);
    h1p_[1] = (short*)alloc((size_t)BB * HN * 2);
    h1l_[1] = (short*)alloc((size_t)BB * HN * 2);
    short* xdh = (short*)alloc((size_t)BB * XWP * 2);
    short* xdl = (short*)alloc((size_t)BB * XWP * 2);
    size_t zlen = (size_t)(p - zbase);

    // ---- prepack ----
    pack_gruw_i<<<4096, 256, 0, stream>>>(wih0, whh0, DN, XWP, KP0, W0h, W0l);
    pack_gruw_i<<<4096, 256, 0, stream>>>(wih1, whh1, HN, HN, KP1, W1h, W1l);
    pack_grub<<<16, 256, 0, stream>>>(bih0, bhh0, b0p);
    pack_grub<<<16, 256, 0, stream>>>(bih1, bhh1, b1p);
    castw<<<1024, 256, 0, stream>>>(freq_w, freqh, freql, DN, KPF);
    castw<<<3072, 256, 0, stream>>>(ain_w, ainh, ainl, HN, HN);
    castw<<<1024, 256, 0, stream>>>(aout_w, aouth, aoutl, HN, HN);
    castw<<<1024, 256, 0, stream>>>(pre_w, preh, prel, HN, HN);
    castw<<<1920, 256, 0, stream>>>(spl_w1, spl1h, spl1l, HN, HN);
    pack_x<<<TSEED, 256, 0, stream>>>(poses, Xh, Xl);
    hipMemsetAsync(zbase, 0, zlen, stream);

    // ---- encoder front ----
    cos_kernel<<<FN, 128, 0, stream>>>(cosm);
    dft_kernel<<<BB, 256, 0, stream>>>(poses, cosm, freqf);
    for (int bc = 0; bc < BB / BCH; ++bc) {
        mgemm<1><<<dim3(RCH / 32, HN / 64), 256, 0, stream>>>(
            freqf + (size_t)bc * RCH * DN, DN, DN, nullptr, nullptr, 0, 0,
            freqh, freql, KPF, freq_b, nullptr, nullptr, feath, featl, HN);
        mgemm<0><<<dim3(RCH / 32, 3 * HN / 64), 256, 0, stream>>>(
            nullptr, 0, 0, feath, featl, HN, HN,
            ainh, ainl, HN, ain_b, nullptr, qkvc, nullptr, nullptr, 3 * HN);
        attn_kernel<<<dim3(BCH, 4), 256, 0, stream>>>(qkvc, obar, bc * BCH);
    }
    mgemm<0><<<dim3(BB / 32, HN / 64), 256, 0, stream>>>(
        obar, HN, HN, nullptr, nullptr, 0, 0,
        aouth, aoutl, HN, aout_b, nullptr, mctx, nullptr, nullptr, HN);
    prep_kernel<<<BB, 128, 0, stream>>>(poses, sixd, xdh, xdl);

    // ---- GRU scan: paired dispatches D_t = { L0(t+1), L1(t) } ----
    auto mkL0 = [&](const short* a1h, const short* a1l, int t) {
        GruArgs g;
        g.A1h = a1h; g.A1l = a1l; g.w1 = XWP; g.s1 = XWP;
        g.A2h = h0p_[(t + 1) & 1]; g.A2l = h0l_[(t + 1) & 1]; g.s2 = HN;
        g.Wh = W0h; g.Wl = W0l; g.KP = KP0; g.NCH = KP0 / 32; g.bp = b0p;
        g.hf = h0f; g.hoh = h0p_[t & 1]; g.hol = h0l_[t & 1];
        return g;
    };
    auto mkL1 = [&](int t) {
        GruArgs g;
        g.A1h = h0p_[t & 1]; g.A1l = h0l_[t & 1]; g.w1 = HN; g.s1 = HN;
        g.A2h = h1p_[(t + 1) & 1]; g.A2l = h1l_[(t + 1) & 1]; g.s2 = HN;
        g.Wh = W1h; g.Wl = W1l; g.KP = KP1; g.NCH = KP1 / 32; g.bp = b1p;
        g.hf = h1f; g.hoh = h1p_[t & 1]; g.hol = h1l_[t & 1];
        return g;
    };
    {
        GruArgs g = mkL0(Xh, Xl, 0);
        gru_pair<<<dim3(4, 64, 1), 256, 0, stream>>>(g, g);
    }
    for (int t = 0; t < TSEED - 1; ++t) {
        GruArgs a = mkL0(Xh + (size_t)(t + 1) * BB * XWP, Xl + (size_t)(t + 1) * BB * XWP, t + 1);
        GruArgs b = mkL1(t);
        gru_pair<<<dim3(4, 64, 2), 256, 0, stream>>>(a, b);
    }
    {
        GruArgs g = mkL1(TSEED - 1);
        gru_pair<<<dim3(4, 64, 1), 256, 0, stream>>>(g, g);
    }

    // ---- decoder ----
    for (int td = 0; td < PREDN; ++td) {
        int t = TSEED + td;
        {
            GruArgs g = mkL0(xdh, xdl, t);
            gru_pair<<<dim3(4, 64, 1), 256, 0, stream>>>(g, g);
        }
        {
            GruArgs g = mkL1(t);
            gru_pair<<<dim3(4, 64, 1), 256, 0, stream>>>(g, g);
        }
        mgemm<2><<<dim3(BB / 32, HN / 64), 256, 0, stream>>>(
            nullptr, 0, 0, h1p_[t & 1], h1l_[t & 1], HN, HN,
            preh, prel, HN, pre_b, mctx, nullptr, hidh, hidl, HN);
        fsplrot<<<dim3(BB / 32, JN), 256, 0, stream>>>(
            hidh, hidl, spl1h, spl1l, spl_b1, spl_w2, spl_b2,
            sixd, out, td, xdh, xdl);
    }
}